// Round 9
// baseline (962.412 us; speedup 1.0000x reference)
//
#include <hip/hip_runtime.h>
#include <hip/hip_bf16.h>
#include <stdint.h>

#define TN 4096      // tokens (B*S)
#define DI 4096      // input dim
#define DH 1376      // GLU hidden dim
#define DHP 1408     // padded hidden (22*64)
#define DO 4096      // output dim
#define NE 8         // experts
#define NPAIR 8192   // TN * K

typedef unsigned short u16;
typedef __bf16 bf16x8 __attribute__((ext_vector_type(8)));
typedef float f32x4 __attribute__((ext_vector_type(4)));
typedef uint32_t u32x4 __attribute__((ext_vector_type(4)));

__device__ __forceinline__ uint32_t pack2bf(float a, float b) {
    union { float f; uint32_t u; } ua, ub;
    ua.f = a; ub.f = b;
    uint32_t lo = (ua.u + 0x7fffu + ((ua.u >> 16) & 1u)) >> 16;
    uint32_t hi = (ub.u + 0x7fffu + ((ub.u >> 16) & 1u)) >> 16;
    return lo | (hi << 16);
}
__device__ __forceinline__ u16 f2bf(float a) {
    union { float f; uint32_t u; } ua; ua.f = a;
    return (u16)((ua.u + 0x7fffu + ((ua.u >> 16) & 1u)) >> 16);
}
__device__ __forceinline__ void gload16(const void* g, void* l) {
    __builtin_amdgcn_global_load_lds(
        (const __attribute__((address_space(1))) void*)g,
        (__attribute__((address_space(3))) void*)l, 16, 0, 0);
}
#define MEMFENCE() asm volatile("" ::: "memory")
#define VMCNT0()   asm volatile("s_waitcnt vmcnt(0)" ::: "memory")
#define BAR()      do { MEMFENCE(); __builtin_amdgcn_s_barrier(); MEMFENCE(); } while (0)
#define LGKM()     do { asm volatile("s_waitcnt lgkmcnt(0)" ::: "memory"); \
                        __builtin_amdgcn_sched_barrier(0); } while (0)

// ---------------- weight converters ----------------
__global__ __launch_bounds__(256) void k_cvt(const float* __restrict__ src,
                                             u16* __restrict__ dst, int n8)
{
    int i = blockIdx.x * 256 + threadIdx.x;
    if (i >= n8) return;
    const float4* s = (const float4*)(src + (size_t)i * 8);
    float4 a = s[0], b = s[1];
    u32x4 q = {pack2bf(a.x, a.y), pack2bf(a.z, a.w), pack2bf(b.x, b.y), pack2bf(b.z, b.w)};
    *(u32x4*)(dst + (size_t)i * 8) = q;
}

__global__ __launch_bounds__(256) void k_cvt_wd(const float* __restrict__ src,
                                                u16* __restrict__ dst)
{
    int i = blockIdx.x * 256 + threadIdx.x;
    int row = i / 176, c8 = (i % 176) * 8;
    u32x4 q = {0u, 0u, 0u, 0u};
    if (c8 < DH) {
        const float4* s = (const float4*)(src + (size_t)row * DH + c8);
        float4 a = s[0], b = s[1];
        q = (u32x4){pack2bf(a.x, a.y), pack2bf(a.z, a.w), pack2bf(b.x, b.y), pack2bf(b.z, b.w)};
    }
    *(u32x4*)(dst + (size_t)row * DHP + c8) = q;
}

// ---------------- Kernel 1: gate (f64-accurate) + x -> bf16 ----------------
__global__ __launch_bounds__(256) void k_gate(
    const float* __restrict__ x, const float* __restrict__ gw,
    u16* __restrict__ x16, int* __restrict__ tke, float* __restrict__ tks,
    int* __restrict__ cnt, float* __restrict__ imp)
{
    int t = blockIdx.x, tid = threadIdx.x;
    const float* xr = x + (size_t)t * DI;
    double acc[NE];
#pragma unroll
    for (int e = 0; e < NE; ++e) acc[e] = 0.0;
#pragma unroll
    for (int j = 0; j < 4; ++j) {
        int i4 = (j * 256 + tid) * 4;
        float4 xv = *(const float4*)(xr + i4);
        uint2 p; p.x = pack2bf(xv.x, xv.y); p.y = pack2bf(xv.z, xv.w);
        *(uint2*)(x16 + (size_t)t * DI + i4) = p;
#pragma unroll
        for (int e = 0; e < NE; ++e) {
            float4 wv = *(const float4*)(gw + (size_t)e * DI + i4);
            acc[e] = fma((double)xv.x, (double)wv.x, acc[e]);
            acc[e] = fma((double)xv.y, (double)wv.y, acc[e]);
            acc[e] = fma((double)xv.z, (double)wv.z, acc[e]);
            acc[e] = fma((double)xv.w, (double)wv.w, acc[e]);
        }
    }
#pragma unroll
    for (int o = 32; o > 0; o >>= 1)
#pragma unroll
        for (int e = 0; e < NE; ++e) acc[e] += __shfl_down(acc[e], o, 64);
    __shared__ double lred[4][NE];
    if ((tid & 63) == 0)
#pragma unroll
        for (int e = 0; e < NE; ++e) lred[tid >> 6][e] = acc[e];
    __syncthreads();
    if (tid == 0) {
        double lg[NE];
#pragma unroll
        for (int e = 0; e < NE; ++e) lg[e] = lred[0][e] + lred[1][e] + lred[2][e] + lred[3][e];
        int e1 = 0;
        for (int e = 1; e < NE; ++e) if (lg[e] > lg[e1]) e1 = e;
        int e2 = -1;
        for (int e = 0; e < NE; ++e) { if (e == e1) continue; if (e2 < 0 || lg[e] > lg[e2]) e2 = e; }
        float d = (float)(lg[e2] - lg[e1]);
        float ed = expf(d);
        float s1 = 1.0f / (1.0f + ed);
        float s2 = ed / (1.0f + ed);
        tke[2 * t] = e1; tke[2 * t + 1] = e2;
        tks[2 * t] = s1; tks[2 * t + 1] = s2;
        atomicAdd(&cnt[e1], 1); atomicAdd(&cnt[e2], 1);
        unsafeAtomicAdd(&imp[e1], s1); unsafeAtomicAdd(&imp[e2], s2);
    }
}

// ---------------- Kernel 2: offsets + gate_loss ----------------
__global__ void k_finalize(const int* __restrict__ cnt, const float* __restrict__ imp,
                           int* __restrict__ off, float* __restrict__ loss_out)
{
    if (threadIdx.x == 0 && blockIdx.x == 0) {
        int o = 0;
        for (int e = 0; e < NE; ++e) { off[e] = o; o += cnt[e]; }
        float m1 = 0.f, m2 = 0.f;
        for (int e = 0; e < NE; ++e) { m1 += imp[e]; m2 += (float)cnt[e]; }
        m1 *= 0.125f; m2 *= 0.125f;
        float v1 = 0.f, v2 = 0.f;
        for (int e = 0; e < NE; ++e) {
            float d1 = imp[e] - m1, d2 = (float)cnt[e] - m2;
            v1 += d1 * d1; v2 += d2 * d2;
        }
        v1 /= 7.0f; v2 /= 7.0f;
        float cv1 = v1 / (m1 * m1 + 1e-10f);
        float cv2 = v2 / (m2 * m2 + 1e-10f);
        *loss_out = 0.01f * (cv1 + cv2);
    }
}

// ---------------- Kernel 3: scatter tokens ----------------
__global__ __launch_bounds__(256) void k_scatter(
    const int* __restrict__ tke, const float* __restrict__ tks,
    const int* __restrict__ off, int* __restrict__ fill,
    int* __restrict__ tok, float* __restrict__ sc)
{
    int t = blockIdx.x * 256 + threadIdx.x;
    if (t >= TN) return;
#pragma unroll
    for (int k = 0; k < 2; ++k) {
        int e = tke[2 * t + k];
        int pos = off[e] + atomicAdd(&fill[e], 1);
        tok[pos] = t; sc[pos] = tks[2 * t + k];
    }
}

// ---------------- Kernel 4: y init with score-weighted b_down ----------------
__global__ __launch_bounds__(256) void k_yinit(
    const int* __restrict__ tke, const float* __restrict__ tks,
    const float* __restrict__ bd, float* __restrict__ y)
{
    int t = blockIdx.x, tid = threadIdx.x;
    int e1 = tke[2 * t], e2 = tke[2 * t + 1];
    float s1 = tks[2 * t], s2 = tks[2 * t + 1];
    const float4* b1 = (const float4*)(bd + (size_t)e1 * DO);
    const float4* b2 = (const float4*)(bd + (size_t)e2 * DO);
    float4* yr = (float4*)(y + (size_t)t * DO);
#pragma unroll
    for (int j = 0; j < 4; ++j) {
        int i = j * 256 + tid;
        float4 a = b1[i], b = b2[i], r;
        r.x = s1 * a.x + s2 * b.x; r.y = s1 * a.y + s2 * b.y;
        r.z = s1 * a.z + s2 * b.z; r.w = s1 * a.w + s2 * b.w;
        yr[i] = r;
    }
}

// ============ 8-wave 8-phase GEMM kernels (m201 template port) ============
// BK=64 -> 128B LDS rows, 8 slots of 16B. XOR swizzle: phys slot p of row r
// holds logical slot p ^ (r&7) (rule-21: pre-swizzled global src, linear LDS
// dest via global_load_lds wave-uniform base, same XOR on read). 2-way bank
// residual = free. Per K-tile: 4 phases, each {ds_read cluster || 2-4 gloads
// -> bar -> lgkmcnt(0)+sched_barrier -> setprio(1) 16 MFMA setprio(0) -> bar};
// vmcnt(0) only at the tile's LAST phase: all 8 prefetch loads issued >=3
// phases earlier stay in flight across 6 barriers (T3+T4), setprio arbitrates
// the wave role-split (T5). Rounds 6-8 proved the coarse 2-phase family caps
// at 26-28% MfmaUtil regardless of buffering depth.
// __launch_bounds__(512,2): 8 waves = 2/SIMD -> 256 reg/thread (acc=128).

// ---------------- stage-1: fused GLU GEMM, 256x128 tile ----------------
__global__ __launch_bounds__(512, 2) void k_s1_8p(
    const u16* __restrict__ x16,
    const u16* __restrict__ wg16, const u16* __restrict__ wu16,
    const float* __restrict__ bg, const float* __restrict__ bu,
    const int* __restrict__ cnt, const int* __restrict__ off,
    const int* __restrict__ tok, const float* __restrict__ sc,
    u16* __restrict__ inter)
{
    int e = blockIdx.x & 7;
    int ce = cnt[e];
    int rows0 = (blockIdx.x >> 3) * 256;
    if (rows0 >= ce) return;
    int oe = off[e];
    int h0 = blockIdx.y * 128;
    int tid = threadIdx.x;

    __shared__ u16 Aa[256 * 64]; __shared__ u16 Ab[256 * 64];   // 32KB each
    __shared__ u16 Ga[128 * 64]; __shared__ u16 Gb[128 * 64];   // 16KB each
    __shared__ u16 Ua[128 * 64]; __shared__ u16 Ub[128 * 64];   // total 128KB

    // staging: thread t fills row (t>>3) of each 64-row group, phys slot t&7;
    // global src logical slot = (t&7) ^ ((t>>3)&7)
    int swz = ((tid & 7) ^ ((tid >> 3) & 7)) * 8;
    int rr = tid >> 3;                   // 0..63
    const u16* ap[4]; const u16* gp[2]; const u16* up[2];
#pragma unroll
    for (int i = 0; i < 4; ++i) {
        int rg = oe + min(rows0 + i * 64 + rr, ce - 1);
        ap[i] = x16 + (size_t)tok[rg] * DI + swz;
    }
#pragma unroll
    for (int j = 0; j < 2; ++j) {
        int hr = min(h0 + j * 64 + rr, DH - 1);
        gp[j] = wg16 + ((size_t)e * DH + hr) * DI + swz;
        up[j] = wu16 + ((size_t)e * DH + hr) * DI + swz;
    }

    int wid = tid >> 6, lane = tid & 63;
    int wm = wid >> 1, wn = wid & 1;     // 4m x 2n wave grid, wave tile 64x64
    int l15 = lane & 15, q = lane >> 4;
    int ph0 = ((q ^ (lane & 7)) & 7) * 8;        // kk=0 phys slot (u16)
    int ph1 = (((4 + q) ^ (lane & 7)) & 7) * 8;  // kk=1
    int rAb = (wm * 64 + l15) * 64;      // frag base: row*64 u16
    int rBb = (wn * 64 + l15) * 64;

    f32x4 accg[4][4], accu[4][4];
    f32x4 vz = {0.f, 0.f, 0.f, 0.f};
#pragma unroll
    for (int m = 0; m < 4; ++m)
#pragma unroll
        for (int n = 0; n < 4; ++n) { accg[m][n] = vz; accu[m][n] = vz; }

#define RD_A(DST, T_, PH) \
    _Pragma("unroll") for (int m = 0; m < 4; ++m) \
        DST[m] = *(const bf16x8*)&T_[rAb + m * 1024 + (PH)];
#define RD_B(DST, T_, PH) \
    _Pragma("unroll") for (int n = 0; n < 4; ++n) \
        DST[n] = *(const bf16x8*)&T_[rBb + n * 1024 + (PH)];
#define MM16(ACC, AV, BV) \
    do { __builtin_amdgcn_s_setprio(1); \
    _Pragma("unroll") for (int m = 0; m < 4; ++m) \
    _Pragma("unroll") for (int n = 0; n < 4; ++n) \
        ACC[m][n] = __builtin_amdgcn_mfma_f32_16x16x32_bf16(AV[m], BV[n], ACC[m][n], 0, 0, 0); \
    __builtin_amdgcn_s_setprio(0); } while (0)
#define STA(T_, K0) \
    _Pragma("unroll") for (int i = 0; i < 4; ++i) \
        gload16(ap[i] + (K0), &T_[i * 4096 + wid * 512]);
#define STGU(G_, U_, K0) \
    _Pragma("unroll") for (int j = 0; j < 2; ++j) { \
        gload16(gp[j] + (K0), &G_[j * 4096 + wid * 512]); \
        gload16(up[j] + (K0), &U_[j * 4096 + wid * 512]); }

#define S1_TILE(A_, G_, U_, An, Gn, Un, K0, DOST)   \
  do {                                              \
    bf16x8 av[4], bv[4];                            \
    RD_A(av, A_, ph0); RD_B(bv, G_, ph0);           \
    if (DOST) { STA(An, K0); }                      \
    BAR(); LGKM();                                  \
    MM16(accg, av, bv);                             \
    BAR();                                          \
    RD_B(bv, U_, ph0);                              \
    if (DOST) { STGU(Gn, Un, K0); }                 \
    BAR(); LGKM();                                  \
    MM16(accu, av, bv);                             \
    BAR();                                          \
    RD_A(av, A_, ph1); RD_B(bv, G_, ph1);           \
    BAR(); LGKM();                                  \
    MM16(accg, av, bv);                             \
    BAR();                                          \
    RD_B(bv, U_, ph1);                              \
    BAR(); LGKM();                                  \
    MM16(accu, av, bv);                             \
    VMCNT0();                                       \
    BAR();                                          \
  } while (0)

    // prologue
    STA(Aa, 0); STGU(Ga, Ua, 0);
    VMCNT0();
    BAR();

    const int NT = DI / 64;   // 64, even
    for (int t = 0; t < NT; t += 2) {
        S1_TILE(Aa, Ga, Ua, Ab, Gb, Ub, (t + 1) * 64, (t + 1) < NT);
        S1_TILE(Ab, Gb, Ub, Aa, Ga, Ua, (t + 2) * 64, (t + 2) < NT);
    }
#undef S1_TILE
#undef STA
#undef STGU
#undef RD_A
#undef RD_B

    // epilogue: bias + silu + score-fold; zero-fill pad cols [DH, DHP)
    int rmax = ce - rows0;
    float bgv[4], buv[4];
    int hc[4]; bool hok[4];
#pragma unroll
    for (int n = 0; n < 4; ++n) {
        hc[n] = h0 + wn * 64 + n * 16 + l15;
        hok[n] = hc[n] < DH;
        bgv[n] = hok[n] ? bg[e * DH + hc[n]] : 0.f;
        buv[n] = hok[n] ? bu[e * DH + hc[n]] : 0.f;
    }
#pragma unroll
    for (int m = 0; m < 4; ++m) {
#pragma unroll
        for (int r = 0; r < 4; ++r) {
            int rl = wm * 64 + m * 16 + q * 4 + r;
            if (rl < rmax) {
                int rg = oe + rows0 + rl;
                float s = sc[rg];
                size_t rowb = (size_t)rg * DHP;
#pragma unroll
                for (int n = 0; n < 4; ++n) {
                    float v = 0.f;
                    if (hok[n]) {
                        float gv = accg[m][n][r] + bgv[n];
                        float uv = accu[m][n][r] + buv[n];
                        float sig = 1.0f / (1.0f + __expf(-gv));
                        v = s * gv * sig * uv;
                    }
                    inter[rowb + hc[n]] = f2bf(v);
                }
            }
        }
    }
}

// ---------------- stage-2: down-proj GEMM + atomic scatter, 256x256 tile ----------------
__global__ __launch_bounds__(512, 2) void k_s2_8p(
    const u16* __restrict__ inter, const u16* __restrict__ wd16,
    const int* __restrict__ cnt, const int* __restrict__ off,
    const int* __restrict__ tok, float* __restrict__ y)
{
    int e = blockIdx.x & 7;
    int ce = cnt[e];
    int rows0 = (blockIdx.x >> 3) * 256;
    if (rows0 >= ce) return;
    int oe = off[e];
    int o0 = blockIdx.y * 256;
    int tid = threadIdx.x;

    __shared__ u16 Aa[256 * 64]; __shared__ u16 Ab[256 * 64];
    __shared__ u16 Ba[256 * 64]; __shared__ u16 Bb[256 * 64];   // 128KB

    int swz = ((tid & 7) ^ ((tid >> 3) & 7)) * 8;
    int rr = tid >> 3;
    const u16* ap[4]; const u16* bp[4];
#pragma unroll
    for (int i = 0; i < 4; ++i) {
        int ar = min(oe + rows0 + i * 64 + rr, NPAIR - 1);
        ap[i] = inter + (size_t)ar * DHP + swz;
        bp[i] = wd16 + ((size_t)e * DO + (o0 + i * 64 + rr)) * DHP + swz;
    }

    int wid = tid >> 6, lane = tid & 63;
    int wm = wid >> 2, wn = wid & 3;     // 2m x 4n wave grid, wave tile 128x64
    int l15 = lane & 15, q = lane >> 4;
    int ph0 = ((q ^ (lane & 7)) & 7) * 8;
    int ph1 = (((4 + q) ^ (lane & 7)) & 7) * 8;
    int rAb = (wm * 128 + l15) * 64;
    int rBb = (wn * 64 + l15) * 64;

    f32x4 acc[8][4];
    f32x4 vz = {0.f, 0.f, 0.f, 0.f};
#pragma unroll
    for (int m = 0; m < 8; ++m)
#pragma unroll
        for (int n = 0; n < 4; ++n) acc[m][n] = vz;

#define RD_A2(DST, T_, PH, MB) \
    _Pragma("unroll") for (int m = 0; m < 4; ++m) \
        DST[m] = *(const bf16x8*)&T_[rAb + ((MB) + m) * 1024 + (PH)];
#define RD_B2(DST, T_, PH) \
    _Pragma("unroll") for (int n = 0; n < 4; ++n) \
        DST[n] = *(const bf16x8*)&T_[rBb + n * 1024 + (PH)];
#define MM16_2(MB, AV, BV) \
    do { __builtin_amdgcn_s_setprio(1); \
    _Pragma("unroll") for (int m = 0; m < 4; ++m) \
    _Pragma("unroll") for (int n = 0; n < 4; ++n) \
        acc[(MB) + m][n] = __builtin_amdgcn_mfma_f32_16x16x32_bf16(AV[m], BV[n], acc[(MB) + m][n], 0, 0, 0); \
    __builtin_amdgcn_s_setprio(0); } while (0)
#define ST4(P_, T_, K0) \
    _Pragma("unroll") for (int i = 0; i < 4; ++i) \
        gload16(P_[i] + (K0), &T_[i * 4096 + wid * 512]);

#define S2_TILE(A_, B_, An, Bn, K0, DOST)           \
  do {                                              \
    bf16x8 av[4], bv[4];                            \
    RD_A2(av, A_, ph0, 0); RD_B2(bv, B_, ph0);      \
    if (DOST) { ST4(ap, An, K0); }                  \
    BAR(); LGKM();                                  \
    MM16_2(0, av, bv);                              \
    BAR();                                          \
    RD_A2(av, A_, ph0, 4);                          \
    if (DOST) { ST4(bp, Bn, K0); }                  \
    BAR(); LGKM();                                  \
    MM16_2(4, av, bv);                              \
    BAR();                                          \
    RD_A2(av, A_, ph1, 0); RD_B2(bv, B_, ph1);      \
    BAR(); LGKM();                                  \
    MM16_2(0, av, bv);                              \
    BAR();                                          \
    RD_A2(av, A_, ph1, 4);                          \
    BAR(); LGKM();                                  \
    MM16_2(4, av, bv);                              \
    VMCNT0();                                       \
    BAR();                                          \
  } while (0)

    ST4(ap, Aa, 0); ST4(bp, Ba, 0);
    VMCNT0();
    BAR();

    const int NT = DHP / 64;   // 22, even
    for (int t = 0; t < NT; t += 2) {
        S2_TILE(Aa, Ba, Ab, Bb, (t + 1) * 64, (t + 1) < NT);
        S2_TILE(Ab, Bb, Aa, Ba, (t + 2) * 64, (t + 2) < NT);
    }
#undef S2_TILE
#undef ST4
#undef RD_A2
#undef RD_B2

    int rmax = ce - rows0;
#pragma unroll
    for (int m = 0; m < 8; ++m) {
#pragma unroll
        for (int r = 0; r < 4; ++r) {
            int rl = wm * 128 + m * 16 + q * 4 + r;
            if (rl >= rmax) continue;
            int t = tok[oe + rows0 + rl];
            float* yr = y + (size_t)t * DO + o0 + wn * 64 + l15;
#pragma unroll
            for (int n = 0; n < 4; ++n)
                unsafeAtomicAdd(yr + n * 16, acc[m][n][r]);
        }
    }
}

// ---------------- host launch ----------------
extern "C" void kernel_launch(void* const* d_in, const int* in_sizes, int n_in,
                              void* d_out, int out_size, void* d_ws, size_t ws_size,
                              hipStream_t stream)
{
    const float* x  = (const float*)d_in[0];
    const float* gw = (const float*)d_in[1];
    const float* wg = (const float*)d_in[2];
    const float* bg = (const float*)d_in[3];
    const float* wu = (const float*)d_in[4];
    const float* bu = (const float*)d_in[5];
    const float* wd = (const float*)d_in[6];
    const float* bd = (const float*)d_in[7];
    float* y = (float*)d_out;
    float* loss = y + (size_t)TN * DO;

    uint8_t* ws = (uint8_t*)d_ws;
    u16*   x16   = (u16*)(ws + 0);             // 33,554,432
    u16*   inter = (u16*)(ws + 33554432ull);   // 23,068,672 (stride DHP)
    u16*   wg16  = (u16*)(ws + 56623104ull);   // 90,177,536
    u16*   wu16  = (u16*)(ws + 146800640ull);  // 90,177,536
    u16*   wd16  = (u16*)(ws + 236978176ull);  // 92,274,688 (stride DHP, pad zeroed)
    int*   tok   = (int*)(ws + 329252864ull);
    float* sc    = (float*)(ws + 329285632ull);
    int*   tke   = (int*)(ws + 329318400ull);
    float* tks   = (float*)(ws + 329351168ull);
    int*   misc  = (int*)(ws + 329383936ull);
    int* cnt = misc; int* fill = misc + 8; int* off = misc + 16;
    float* imp = (float*)(misc + 24);

    hipMemsetAsync(misc, 0, 128, stream);
    k_cvt<<<22016, 256, 0, stream>>>(wg, wg16, 5636096);
    k_cvt<<<22016, 256, 0, stream>>>(wu, wu16, 5636096);
    k_cvt_wd<<<22528, 256, 0, stream>>>(wd, wd16);
    k_gate<<<TN, 256, 0, stream>>>(x, gw, x16, tke, tks, cnt, imp);
    k_finalize<<<1, 64, 0, stream>>>(cnt, imp, off, loss);
    k_scatter<<<TN / 256, 256, 0, stream>>>(tke, tks, off, fill, tok, sc);
    k_yinit<<<TN, 256, 0, stream>>>(tke, tks, bd, y);
    k_s1_8p<<<dim3(128, 11), 512, 0, stream>>>(x16, wg16, wu16, bg, bu, cnt, off, tok, sc, inter);
    k_s2_8p<<<dim3(128, 16), 512, 0, stream>>>(inter, wd16, cnt, off, tok, y);
}

// Round 10
// 929.131 us; speedup vs baseline: 1.0358x; 1.0358x over previous
//
#include <hip/hip_runtime.h>
#include <hip/hip_bf16.h>
#include <stdint.h>

#define TN 4096      // tokens (B*S)
#define DI 4096      // input dim
#define DH 1376      // GLU hidden dim
#define DHP 1408     // padded hidden (22*64)
#define DO 4096      // output dim
#define NE 8         // experts
#define NPAIR 8192   // TN * K

typedef unsigned short u16;
typedef __bf16 bf16x8 __attribute__((ext_vector_type(8)));
typedef float f32x4 __attribute__((ext_vector_type(4)));
typedef uint32_t u32x4 __attribute__((ext_vector_type(4)));

__device__ __forceinline__ uint32_t pack2bf(float a, float b) {
    union { float f; uint32_t u; } ua, ub;
    ua.f = a; ub.f = b;
    uint32_t lo = (ua.u + 0x7fffu + ((ua.u >> 16) & 1u)) >> 16;
    uint32_t hi = (ub.u + 0x7fffu + ((ub.u >> 16) & 1u)) >> 16;
    return lo | (hi << 16);
}
__device__ __forceinline__ u16 f2bf(float a) {
    union { float f; uint32_t u; } ua; ua.f = a;
    return (u16)((ua.u + 0x7fffu + ((ua.u >> 16) & 1u)) >> 16);
}
__device__ __forceinline__ void gload16(const void* g, void* l) {
    __builtin_amdgcn_global_load_lds(
        (const __attribute__((address_space(1))) void*)g,
        (__attribute__((address_space(3))) void*)l, 16, 0, 0);
}
#define MEMFENCE() asm volatile("" ::: "memory")

// ---------------- merged weight converter ----------------
// region 0: wg  [8*1376*4096] f32 -> bf16       (5,636,096 groups of 8)
// region 1: wu  same                             (5,636,096)
// region 2: wd  [8*4096][1376] -> [..][1408] pad (32768*176 = 5,767,168)
__global__ __launch_bounds__(256) void k_cvt_all(
    const float* __restrict__ wg, const float* __restrict__ wu,
    const float* __restrict__ wd,
    u16* __restrict__ wg16, u16* __restrict__ wu16, u16* __restrict__ wd16)
{
    int i = blockIdx.x * 256 + threadIdx.x;
    if (i < 11272192) {
        const float* src = (i < 5636096) ? wg : wu;
        u16* dst = (i < 5636096) ? wg16 : wu16;
        int j = (i < 5636096) ? i : i - 5636096;
        const float4* s = (const float4*)(src + (size_t)j * 8);
        float4 a = s[0], b = s[1];
        u32x4 q = {pack2bf(a.x, a.y), pack2bf(a.z, a.w), pack2bf(b.x, b.y), pack2bf(b.z, b.w)};
        *(u32x4*)(dst + (size_t)j * 8) = q;
    } else {
        int j = i - 11272192;
        if (j >= 5767168) return;
        int row = j / 176, c8 = (j % 176) * 8;
        u32x4 q = {0u, 0u, 0u, 0u};
        if (c8 < DH) {
            const float4* s = (const float4*)(wd + (size_t)row * DH + c8);
            float4 a = s[0], b = s[1];
            q = (u32x4){pack2bf(a.x, a.y), pack2bf(a.z, a.w), pack2bf(b.x, b.y), pack2bf(b.z, b.w)};
        }
        *(u32x4*)(wd16 + (size_t)row * DHP + c8) = q;
    }
}

// ---------------- Kernel 1: gate (f64-accurate) + x -> bf16 ----------------
__global__ __launch_bounds__(256) void k_gate(
    const float* __restrict__ x, const float* __restrict__ gw,
    u16* __restrict__ x16, int* __restrict__ tke, float* __restrict__ tks,
    int* __restrict__ cnt, float* __restrict__ imp)
{
    int t = blockIdx.x, tid = threadIdx.x;
    const float* xr = x + (size_t)t * DI;
    double acc[NE];
#pragma unroll
    for (int e = 0; e < NE; ++e) acc[e] = 0.0;
#pragma unroll
    for (int j = 0; j < 4; ++j) {
        int i4 = (j * 256 + tid) * 4;
        float4 xv = *(const float4*)(xr + i4);
        uint2 p; p.x = pack2bf(xv.x, xv.y); p.y = pack2bf(xv.z, xv.w);
        *(uint2*)(x16 + (size_t)t * DI + i4) = p;
#pragma unroll
        for (int e = 0; e < NE; ++e) {
            float4 wv = *(const float4*)(gw + (size_t)e * DI + i4);
            acc[e] = fma((double)xv.x, (double)wv.x, acc[e]);
            acc[e] = fma((double)xv.y, (double)wv.y, acc[e]);
            acc[e] = fma((double)xv.z, (double)wv.z, acc[e]);
            acc[e] = fma((double)xv.w, (double)wv.w, acc[e]);
        }
    }
#pragma unroll
    for (int o = 32; o > 0; o >>= 1)
#pragma unroll
        for (int e = 0; e < NE; ++e) acc[e] += __shfl_down(acc[e], o, 64);
    __shared__ double lred[4][NE];
    if ((tid & 63) == 0)
#pragma unroll
        for (int e = 0; e < NE; ++e) lred[tid >> 6][e] = acc[e];
    __syncthreads();
    if (tid == 0) {
        double lg[NE];
#pragma unroll
        for (int e = 0; e < NE; ++e) lg[e] = lred[0][e] + lred[1][e] + lred[2][e] + lred[3][e];
        int e1 = 0;
        for (int e = 1; e < NE; ++e) if (lg[e] > lg[e1]) e1 = e;
        int e2 = -1;
        for (int e = 0; e < NE; ++e) { if (e == e1) continue; if (e2 < 0 || lg[e] > lg[e2]) e2 = e; }
        float d = (float)(lg[e2] - lg[e1]);
        float ed = expf(d);
        float s1 = 1.0f / (1.0f + ed);
        float s2 = ed / (1.0f + ed);
        tke[2 * t] = e1; tke[2 * t + 1] = e2;
        tks[2 * t] = s1; tks[2 * t + 1] = s2;
        atomicAdd(&cnt[e1], 1); atomicAdd(&cnt[e2], 1);
        unsafeAtomicAdd(&imp[e1], s1); unsafeAtomicAdd(&imp[e2], s2);
    }
}

// ---------------- Kernel 2: offsets + gate_loss ----------------
__global__ void k_finalize(const int* __restrict__ cnt, const float* __restrict__ imp,
                           int* __restrict__ off, float* __restrict__ loss_out)
{
    if (threadIdx.x == 0 && blockIdx.x == 0) {
        int o = 0;
        for (int e = 0; e < NE; ++e) { off[e] = o; o += cnt[e]; }
        float m1 = 0.f, m2 = 0.f;
        for (int e = 0; e < NE; ++e) { m1 += imp[e]; m2 += (float)cnt[e]; }
        m1 *= 0.125f; m2 *= 0.125f;
        float v1 = 0.f, v2 = 0.f;
        for (int e = 0; e < NE; ++e) {
            float d1 = imp[e] - m1, d2 = (float)cnt[e] - m2;
            v1 += d1 * d1; v2 += d2 * d2;
        }
        v1 /= 7.0f; v2 /= 7.0f;
        float cv1 = v1 / (m1 * m1 + 1e-10f);
        float cv2 = v2 / (m2 * m2 + 1e-10f);
        *loss_out = 0.01f * (cv1 + cv2);
    }
}

// ---------------- Kernel 3: scatter tokens ----------------
__global__ __launch_bounds__(256) void k_scatter(
    const int* __restrict__ tke, const float* __restrict__ tks,
    const int* __restrict__ off, int* __restrict__ fill,
    int* __restrict__ tok, float* __restrict__ sc)
{
    int t = blockIdx.x * 256 + threadIdx.x;
    if (t >= TN) return;
#pragma unroll
    for (int k = 0; k < 2; ++k) {
        int e = tke[2 * t + k];
        int pos = off[e] + atomicAdd(&fill[e], 1);
        tok[pos] = t; sc[pos] = tks[2 * t + k];
    }
}

// ---------------- Kernel 4: y init with score-weighted b_down ----------------
__global__ __launch_bounds__(256) void k_yinit(
    const int* __restrict__ tke, const float* __restrict__ tks,
    const float* __restrict__ bd, float* __restrict__ y)
{
    int t = blockIdx.x, tid = threadIdx.x;
    int e1 = tke[2 * t], e2 = tke[2 * t + 1];
    float s1 = tks[2 * t], s2 = tks[2 * t + 1];
    const float4* b1 = (const float4*)(bd + (size_t)e1 * DO);
    const float4* b2 = (const float4*)(bd + (size_t)e2 * DO);
    float4* yr = (float4*)(y + (size_t)t * DO);
#pragma unroll
    for (int j = 0; j < 4; ++j) {
        int i = j * 256 + tid;
        float4 a = b1[i], b = b2[i], r;
        r.x = s1 * a.x + s2 * b.x; r.y = s1 * a.y + s2 * b.y;
        r.z = s1 * a.z + s2 * b.z; r.w = s1 * a.w + s2 * b.w;
        yr[i] = r;
    }
}

// ============ stage-1: round-7 best (3-buffer counted vmcnt) ============
__global__ __launch_bounds__(256, 2) void k_stage1g(
    const u16* __restrict__ x16,
    const u16* __restrict__ wg16, const u16* __restrict__ wu16,
    const float* __restrict__ bg, const float* __restrict__ bu,
    const int* __restrict__ cnt, const int* __restrict__ off,
    const int* __restrict__ tok, const float* __restrict__ sc,
    u16* __restrict__ inter)
{
    int e = blockIdx.x & 7;
    int ce = cnt[e];
    int rows0 = (blockIdx.x >> 3) * 128;
    if (rows0 >= ce) return;
    int oe = off[e];
    int h0 = blockIdx.y * 128;
    int tid = threadIdx.x;

    __shared__ u16 As0[128 * 32]; __shared__ u16 As1[128 * 32]; __shared__ u16 As2[128 * 32];
    __shared__ u16 Gs0[128 * 32]; __shared__ u16 Gs1[128 * 32]; __shared__ u16 Gs2[128 * 32];
    __shared__ u16 Us0[128 * 32]; __shared__ u16 Us1[128 * 32]; __shared__ u16 Us2[128 * 32];

    int swz = ((tid & 3) ^ ((tid >> 3) & 3)) * 8;
    const u16* ab0; const u16* ab1; const u16* gb0; const u16* gb1;
    const u16* ub0; const u16* ub1;
    {
        int rl0 = tid >> 2, rl1 = 64 + (tid >> 2);
        int rg0 = oe + min(rows0 + rl0, ce - 1);
        int rg1 = oe + min(rows0 + rl1, ce - 1);
        ab0 = x16 + (size_t)tok[rg0] * DI + swz;
        ab1 = x16 + (size_t)tok[rg1] * DI + swz;
        int hr0 = min(h0 + rl0, DH - 1), hr1 = min(h0 + rl1, DH - 1);
        gb0 = wg16 + ((size_t)e * DH + hr0) * DI + swz;
        gb1 = wg16 + ((size_t)e * DH + hr1) * DI + swz;
        ub0 = wu16 + ((size_t)e * DH + hr0) * DI + swz;
        ub1 = wu16 + ((size_t)e * DH + hr1) * DI + swz;
    }

    int wid = tid >> 6, lane = tid & 63;
    int ldsw = wid * 512;
    int wm = wid >> 1, wn = wid & 1;
    int rA = wm * 64 + (lane & 15);
    int rB = wn * 64 + (lane & 15);
    int colb = (((lane >> 4) ^ ((lane >> 1) & 3)) & 3) * 8;

    f32x4 accg[4][4], accu[4][4];
    f32x4 vz = {0.f, 0.f, 0.f, 0.f};
#pragma unroll
    for (int m = 0; m < 4; ++m)
#pragma unroll
        for (int n = 0; n < 4; ++n) { accg[m][n] = vz; accu[m][n] = vz; }

#define S1_STAGE(A_, G_, U_, K0)                                   \
    do {                                                           \
        gload16(ab0 + (K0), &A_[ldsw]);                            \
        gload16(ab1 + (K0), &A_[2048 + ldsw]);                     \
        gload16(gb0 + (K0), &G_[ldsw]);                            \
        gload16(gb1 + (K0), &G_[2048 + ldsw]);                     \
        gload16(ub0 + (K0), &U_[ldsw]);                            \
        gload16(ub1 + (K0), &U_[2048 + ldsw]);                     \
    } while (0)

#define S1_COMPUTE(A_, G_, U_)                                     \
    do {                                                           \
        bf16x8 a[4], g[4], u[4];                                   \
        _Pragma("unroll")                                          \
        for (int m = 0; m < 4; ++m)                                \
            a[m] = *(const bf16x8*)&A_[(rA + m * 16) * 32 + colb]; \
        _Pragma("unroll")                                          \
        for (int n = 0; n < 4; ++n) {                              \
            g[n] = *(const bf16x8*)&G_[(rB + n * 16) * 32 + colb]; \
            u[n] = *(const bf16x8*)&U_[(rB + n * 16) * 32 + colb]; \
        }                                                          \
        __builtin_amdgcn_s_setprio(1);                             \
        _Pragma("unroll")                                          \
        for (int m = 0; m < 4; ++m)                                \
            _Pragma("unroll")                                      \
            for (int n = 0; n < 4; ++n) {                          \
                accg[m][n] = __builtin_amdgcn_mfma_f32_16x16x32_bf16(a[m], g[n], accg[m][n], 0, 0, 0); \
                accu[m][n] = __builtin_amdgcn_mfma_f32_16x16x32_bf16(a[m], u[n], accu[m][n], 0, 0, 0); \
            }                                                      \
        __builtin_amdgcn_s_setprio(0);                             \
    } while (0)

#define S1_PHASE(A_, G_, U_, KN)                                   \
    do {                                                           \
        asm volatile("s_waitcnt vmcnt(12)" ::: "memory");          \
        __builtin_amdgcn_s_barrier();                              \
        MEMFENCE();                                                \
        S1_COMPUTE(A_, G_, U_);                                    \
        __builtin_amdgcn_s_barrier();                              \
        MEMFENCE();                                                \
        S1_STAGE(A_, G_, U_, KN);                                  \
    } while (0)

    const int NT = DI / 32;        // 128
    const int KL = (NT - 1) * 32;
    S1_STAGE(As0, Gs0, Us0, 0);
    S1_STAGE(As1, Gs1, Us1, 32);
    S1_STAGE(As2, Gs2, Us2, 64);

    for (int kt = 0; kt + 4 < NT; kt += 3) {
        S1_PHASE(As0, Gs0, Us0, min((kt + 3) * 32, KL));
        S1_PHASE(As1, Gs1, Us1, min((kt + 4) * 32, KL));
        S1_PHASE(As2, Gs2, Us2, min((kt + 5) * 32, KL));
    }
    asm volatile("s_waitcnt vmcnt(12)" ::: "memory");
    __builtin_amdgcn_s_barrier();
    MEMFENCE();
    S1_COMPUTE(As0, Gs0, Us0);
    asm volatile("s_waitcnt vmcnt(6)" ::: "memory");
    __builtin_amdgcn_s_barrier();
    MEMFENCE();
    S1_COMPUTE(As1, Gs1, Us1);
    asm volatile("s_waitcnt vmcnt(0)" ::: "memory");
#undef S1_STAGE
#undef S1_COMPUTE
#undef S1_PHASE

    int rmax = ce - rows0;
    float bgv[4], buv[4];
    int hc[4]; bool hok[4];
#pragma unroll
    for (int n = 0; n < 4; ++n) {
        hc[n] = h0 + wn * 64 + n * 16 + (lane & 15);
        hok[n] = hc[n] < DH;
        bgv[n] = hok[n] ? bg[e * DH + hc[n]] : 0.f;
        buv[n] = hok[n] ? bu[e * DH + hc[n]] : 0.f;
    }
#pragma unroll
    for (int m = 0; m < 4; ++m) {
#pragma unroll
        for (int r = 0; r < 4; ++r) {
            int rl = wm * 64 + m * 16 + (lane >> 4) * 4 + r;
            if (rl < rmax) {
                int rg = oe + rows0 + rl;
                float s = sc[rg];
                size_t rowb = (size_t)rg * DHP;
#pragma unroll
                for (int n = 0; n < 4; ++n) {
                    float v = 0.f;
                    if (hok[n]) {
                        float gv = accg[m][n][r] + bgv[n];
                        float uv = accu[m][n][r] + buv[n];
                        float sig = 1.0f / (1.0f + __expf(-gv));
                        v = s * gv * sig * uv;
                    }
                    inter[rowb + hc[n]] = f2bf(v);
                }
            }
        }
    }
}

// ============ stage-2: NEW 256x128 tile, wave 128x64 (2x FLOP/LDS-byte) ============
// 4 waves (2M x 2N), acc 8x4 f32x4 = 128 regs; BK=64 ([*][64] tiles, 128B
// rows, 8-slot XOR swizzle: phys slot p of row r holds logical p ^ (r&7) —
// proven 2-way-free). 2-buffer counted-vmcnt(12) r8-style schedule.
__global__ __launch_bounds__(256, 2) void k_stage2i(
    const u16* __restrict__ inter, const u16* __restrict__ wd16,
    const int* __restrict__ cnt, const int* __restrict__ off,
    const int* __restrict__ tok, float* __restrict__ y)
{
    int e = blockIdx.x & 7;
    int ce = cnt[e];
    int rows0 = (blockIdx.x >> 3) * 256;
    if (rows0 >= ce) return;
    int oe = off[e];
    int o0 = blockIdx.y * 128;
    int tid = threadIdx.x;

    __shared__ u16 As0[256 * 64]; __shared__ u16 As1[256 * 64];   // 32KB each
    __shared__ u16 Bs0[128 * 64]; __shared__ u16 Bs1[128 * 64];   // 16KB each

    // staging: thread t fills phys slot (t&7) of row (t>>3) within each
    // 32-row group; global src logical slot = (t&7) ^ ((t>>3)&7)
    int swz = ((tid & 7) ^ ((tid >> 3) & 7)) * 8;
    int rr = tid >> 3;                   // 0..31
    const u16* ap[8]; const u16* bp[4];
#pragma unroll
    for (int i = 0; i < 8; ++i) {
        int ar = min(oe + rows0 + i * 32 + rr, NPAIR - 1);
        ap[i] = inter + (size_t)ar * DHP + swz;
    }
#pragma unroll
    for (int j = 0; j < 4; ++j)
        bp[j] = wd16 + ((size_t)e * DO + (o0 + j * 32 + rr)) * DHP + swz;

    int wid = tid >> 6, lane = tid & 63;
    int ldsw = wid * 512;                // wave-uniform dest base (u16)
    int wm = wid >> 1, wn = wid & 1;     // wave tile 128 rows x 64 cols
    int l15 = lane & 15, q = lane >> 4;
    int s7 = lane & 7;
    int cb0 = ((q ^ s7) & 7) * 8;        // kk0 phys slot
    int cb1 = (((4 + q) ^ s7) & 7) * 8;  // kk1 phys slot
    int rAb = (wm * 128 + l15) * 64;
    int rBb = (wn * 64 + l15) * 64;

    f32x4 acc[8][4];
    f32x4 vz = {0.f, 0.f, 0.f, 0.f};
#pragma unroll
    for (int m = 0; m < 8; ++m)
#pragma unroll
        for (int n = 0; n < 4; ++n) acc[m][n] = vz;

#define S2_STAGE(A_, B_, K0)                                       \
    do {                                                           \
        _Pragma("unroll")                                          \
        for (int i = 0; i < 8; ++i)                                \
            gload16(ap[i] + (K0), &A_[i * 2048 + ldsw]);           \
        _Pragma("unroll")                                          \
        for (int j = 0; j < 4; ++j)                                \
            gload16(bp[j] + (K0), &B_[j * 2048 + ldsw]);           \
    } while (0)

#define S2_COMPUTE(A_, B_)                                         \
    do {                                                           \
        bf16x8 av[8], bv[4];                                       \
        _Pragma("unroll")                                          \
        for (int m = 0; m < 8; ++m)                                \
            av[m] = *(const bf16x8*)&A_[rAb + m * 1024 + cb0];     \
        _Pragma("unroll")                                          \
        for (int n = 0; n < 4; ++n)                                \
            bv[n] = *(const bf16x8*)&B_[rBb + n * 1024 + cb0];     \
        __builtin_amdgcn_s_setprio(1);                             \
        _Pragma("unroll")                                          \
        for (int m = 0; m < 8; ++m)                                \
            _Pragma("unroll")                                      \
            for (int n = 0; n < 4; ++n)                            \
                acc[m][n] = __builtin_amdgcn_mfma_f32_16x16x32_bf16(av[m], bv[n], acc[m][n], 0, 0, 0); \
        __builtin_amdgcn_s_setprio(0);                             \
        _Pragma("unroll")                                          \
        for (int m = 0; m < 8; ++m)                                \
            av[m] = *(const bf16x8*)&A_[rAb + m * 1024 + cb1];     \
        _Pragma("unroll")                                          \
        for (int n = 0; n < 4; ++n)                                \
            bv[n] = *(const bf16x8*)&B_[rBb + n * 1024 + cb1];     \
        __builtin_amdgcn_s_setprio(1);                             \
        _Pragma("unroll")                                          \
        for (int m = 0; m < 8; ++m)                                \
            _Pragma("unroll")                                      \
            for (int n = 0; n < 4; ++n)                            \
                acc[m][n] = __builtin_amdgcn_mfma_f32_16x16x32_bf16(av[m], bv[n], acc[m][n], 0, 0, 0); \
        __builtin_amdgcn_s_setprio(0);                             \
    } while (0)

    const int NT = DHP / 64;       // 22, even
    S2_STAGE(As0, Bs0, 0);
    S2_STAGE(As1, Bs1, 64);

    for (int kt = 0; kt < NT - 2; kt += 2) {
        asm volatile("s_waitcnt vmcnt(12)" ::: "memory");
        __builtin_amdgcn_s_barrier();
        MEMFENCE();
        S2_COMPUTE(As0, Bs0);
        __builtin_amdgcn_s_barrier();
        MEMFENCE();
        S2_STAGE(As0, Bs0, (kt + 2) * 64);
        asm volatile("s_waitcnt vmcnt(12)" ::: "memory");
        __builtin_amdgcn_s_barrier();
        MEMFENCE();
        S2_COMPUTE(As1, Bs1);
        __builtin_amdgcn_s_barrier();
        MEMFENCE();
        S2_STAGE(As1, Bs1, (kt + 3) * 64);
    }
    asm volatile("s_waitcnt vmcnt(12)" ::: "memory");
    __builtin_amdgcn_s_barrier();
    MEMFENCE();
    S2_COMPUTE(As0, Bs0);
    asm volatile("s_waitcnt vmcnt(0)" ::: "memory");
    __builtin_amdgcn_s_barrier();
    MEMFENCE();
    S2_COMPUTE(As1, Bs1);
#undef S2_STAGE
#undef S2_COMPUTE

    int rmax = ce - rows0;
#pragma unroll
    for (int m = 0; m < 8; ++m) {
#pragma unroll
        for (int r = 0; r < 4; ++r) {
            int rl = wm * 128 + m * 16 + q * 4 + r;
            if (rl >= rmax) continue;
            int t = tok[oe + rows0 + rl];
            float* yr = y + (size_t)t * DO + o0 + wn * 64 + l15;
#pragma unroll
            for (int n = 0; n < 4; ++n)
                unsafeAtomicAdd(yr + n * 16, acc[m][n][r]);
        }
    }
}

// ---------------- host launch ----------------
extern "C" void kernel_launch(void* const* d_in, const int* in_sizes, int n_in,
                              void* d_out, int out_size, void* d_ws, size_t ws_size,
                              hipStream_t stream)
{
    const float* x  = (const float*)d_in[0];
    const float* gw = (const float*)d_in[1];
    const float* wg = (const float*)d_in[2];
    const float* bg = (const float*)d_in[3];
    const float* wu = (const float*)d_in[4];
    const float* bu = (const float*)d_in[5];
    const float* wd = (const float*)d_in[6];
    const float* bd = (const float*)d_in[7];
    float* y = (float*)d_out;
    float* loss = y + (size_t)TN * DO;

    uint8_t* ws = (uint8_t*)d_ws;
    u16*   x16   = (u16*)(ws + 0);             // 33,554,432
    u16*   inter = (u16*)(ws + 33554432ull);   // 23,068,672 (stride DHP)
    u16*   wg16  = (u16*)(ws + 56623104ull);   // 90,177,536
    u16*   wu16  = (u16*)(ws + 146800640ull);  // 90,177,536
    u16*   wd16  = (u16*)(ws + 236978176ull);  // 92,274,688 (stride DHP, pad zeroed)
    int*   tok   = (int*)(ws + 329252864ull);
    float* sc    = (float*)(ws + 329285632ull);
    int*   tke   = (int*)(ws + 329318400ull);
    float* tks   = (float*)(ws + 329351168ull);
    int*   misc  = (int*)(ws + 329383936ull);
    int* cnt = misc; int* fill = misc + 8; int* off = misc + 16;
    float* imp = (float*)(misc + 24);

    hipMemsetAsync(misc, 0, 128, stream);
    k_cvt_all<<<66560, 256, 0, stream>>>(wg, wu, wd, wg16, wu16, wd16);
    k_gate<<<TN, 256, 0, stream>>>(x, gw, x16, tke, tks, cnt, imp);
    k_finalize<<<1, 64, 0, stream>>>(cnt, imp, off, loss);
    k_scatter<<<TN / 256, 256, 0, stream>>>(tke, tks, off, fill, tok, sc);
    k_yinit<<<TN, 256, 0, stream>>>(tke, tks, bd, y);
    k_stage1g<<<dim3(256, 11), 256, 0, stream>>>(x16, wg16, wu16, bg, bu, cnt, off, tok, sc, inter);
    k_stage2i<<<dim3(128, 32), 256, 0, stream>>>(inter, wd16, cnt, off, tok, y);
}

// Round 11
// 877.091 us; speedup vs baseline: 1.0973x; 1.0593x over previous
//
#include <hip/hip_runtime.h>
#include <hip/hip_bf16.h>
#include <stdint.h>

#define TN 4096      // tokens (B*S)
#define DI 4096      // input dim
#define DH 1376      // GLU hidden dim
#define DHP 1408     // padded hidden (22*64)
#define DO 4096      // output dim
#define NE 8         // experts
#define NPAIR 8192   // TN * K

typedef unsigned short u16;
typedef __bf16 bf16x8 __attribute__((ext_vector_type(8)));
typedef float f32x4 __attribute__((ext_vector_type(4)));
typedef uint32_t u32x4 __attribute__((ext_vector_type(4)));

__device__ __forceinline__ uint32_t pack2bf(float a, float b) {
    union { float f; uint32_t u; } ua, ub;
    ua.f = a; ub.f = b;
    uint32_t lo = (ua.u + 0x7fffu + ((ua.u >> 16) & 1u)) >> 16;
    uint32_t hi = (ub.u + 0x7fffu + ((ub.u >> 16) & 1u)) >> 16;
    return lo | (hi << 16);
}
__device__ __forceinline__ u16 f2bf(float a) {
    union { float f; uint32_t u; } ua; ua.f = a;
    return (u16)((ua.u + 0x7fffu + ((ua.u >> 16) & 1u)) >> 16);
}
__device__ __forceinline__ void gload16(const void* g, void* l) {
    __builtin_amdgcn_global_load_lds(
        (const __attribute__((address_space(1))) void*)g,
        (__attribute__((address_space(3))) void*)l, 16, 0, 0);
}
#define MEMFENCE() asm volatile("" ::: "memory")
#define BAR()  do { MEMFENCE(); __builtin_amdgcn_s_barrier(); MEMFENCE(); } while (0)
#define LGKM() do { asm volatile("s_waitcnt lgkmcnt(0)" ::: "memory"); \
                    __builtin_amdgcn_sched_barrier(0); } while (0)
#define VMW(N) asm volatile("s_waitcnt vmcnt(" #N ")" ::: "memory")

// ---------------- merged weight converter ----------------
__global__ __launch_bounds__(256) void k_cvt_all(
    const float* __restrict__ wg, const float* __restrict__ wu,
    const float* __restrict__ wd,
    u16* __restrict__ wg16, u16* __restrict__ wu16, u16* __restrict__ wd16)
{
    int i = blockIdx.x * 256 + threadIdx.x;
    if (i < 11272192) {
        const float* src = (i < 5636096) ? wg : wu;
        u16* dst = (i < 5636096) ? wg16 : wu16;
        int j = (i < 5636096) ? i : i - 5636096;
        const float4* s = (const float4*)(src + (size_t)j * 8);
        float4 a = s[0], b = s[1];
        u32x4 v = {pack2bf(a.x, a.y), pack2bf(a.z, a.w), pack2bf(b.x, b.y), pack2bf(b.z, b.w)};
        *(u32x4*)(dst + (size_t)j * 8) = v;
    } else {
        int j = i - 11272192;
        if (j >= 5767168) return;
        int row = j / 176, c8 = (j % 176) * 8;
        u32x4 v = {0u, 0u, 0u, 0u};
        if (c8 < DH) {
            const float4* s = (const float4*)(wd + (size_t)row * DH + c8);
            float4 a = s[0], b = s[1];
            v = (u32x4){pack2bf(a.x, a.y), pack2bf(a.z, a.w), pack2bf(b.x, b.y), pack2bf(b.z, b.w)};
        }
        *(u32x4*)(wd16 + (size_t)row * DHP + c8) = v;
    }
}

// ---------------- gate (f64-accurate) + x -> bf16 ----------------
__global__ __launch_bounds__(256) void k_gate(
    const float* __restrict__ x, const float* __restrict__ gw,
    u16* __restrict__ x16, int* __restrict__ tke, float* __restrict__ tks,
    int* __restrict__ cnt, float* __restrict__ imp)
{
    int t = blockIdx.x, tid = threadIdx.x;
    const float* xr = x + (size_t)t * DI;
    double acc[NE];
#pragma unroll
    for (int e = 0; e < NE; ++e) acc[e] = 0.0;
#pragma unroll
    for (int j = 0; j < 4; ++j) {
        int i4 = (j * 256 + tid) * 4;
        float4 xv = *(const float4*)(xr + i4);
        uint2 p; p.x = pack2bf(xv.x, xv.y); p.y = pack2bf(xv.z, xv.w);
        *(uint2*)(x16 + (size_t)t * DI + i4) = p;
#pragma unroll
        for (int e = 0; e < NE; ++e) {
            float4 wv = *(const float4*)(gw + (size_t)e * DI + i4);
            acc[e] = fma((double)xv.x, (double)wv.x, acc[e]);
            acc[e] = fma((double)xv.y, (double)wv.y, acc[e]);
            acc[e] = fma((double)xv.z, (double)wv.z, acc[e]);
            acc[e] = fma((double)xv.w, (double)wv.w, acc[e]);
        }
    }
#pragma unroll
    for (int o = 32; o > 0; o >>= 1)
#pragma unroll
        for (int e = 0; e < NE; ++e) acc[e] += __shfl_down(acc[e], o, 64);
    __shared__ double lred[4][NE];
    if ((tid & 63) == 0)
#pragma unroll
        for (int e = 0; e < NE; ++e) lred[tid >> 6][e] = acc[e];
    __syncthreads();
    if (tid == 0) {
        double lg[NE];
#pragma unroll
        for (int e = 0; e < NE; ++e) lg[e] = lred[0][e] + lred[1][e] + lred[2][e] + lred[3][e];
        int e1 = 0;
        for (int e = 1; e < NE; ++e) if (lg[e] > lg[e1]) e1 = e;
        int e2 = -1;
        for (int e = 0; e < NE; ++e) { if (e == e1) continue; if (e2 < 0 || lg[e] > lg[e2]) e2 = e; }
        float d = (float)(lg[e2] - lg[e1]);
        float ed = expf(d);
        float s1 = 1.0f / (1.0f + ed);
        float s2 = ed / (1.0f + ed);
        tke[2 * t] = e1; tke[2 * t + 1] = e2;
        tks[2 * t] = s1; tks[2 * t + 1] = s2;
        atomicAdd(&cnt[e1], 1); atomicAdd(&cnt[e2], 1);
        unsafeAtomicAdd(&imp[e1], s1); unsafeAtomicAdd(&imp[e2], s2);
    }
}

// ---------------- offsets + gate_loss ----------------
__global__ void k_finalize(const int* __restrict__ cnt, const float* __restrict__ imp,
                           int* __restrict__ off, float* __restrict__ loss_out)
{
    if (threadIdx.x == 0 && blockIdx.x == 0) {
        int o = 0;
        for (int e = 0; e < NE; ++e) { off[e] = o; o += cnt[e]; }
        float m1 = 0.f, m2 = 0.f;
        for (int e = 0; e < NE; ++e) { m1 += imp[e]; m2 += (float)cnt[e]; }
        m1 *= 0.125f; m2 *= 0.125f;
        float v1 = 0.f, v2 = 0.f;
        for (int e = 0; e < NE; ++e) {
            float d1 = imp[e] - m1, d2 = (float)cnt[e] - m2;
            v1 += d1 * d1; v2 += d2 * d2;
        }
        v1 /= 7.0f; v2 /= 7.0f;
        float cv1 = v1 / (m1 * m1 + 1e-10f);
        float cv2 = v2 / (m2 * m2 + 1e-10f);
        *loss_out = 0.01f * (cv1 + cv2);
    }
}

// ---------------- scatter tokens ----------------
__global__ __launch_bounds__(256) void k_scatter(
    const int* __restrict__ tke, const float* __restrict__ tks,
    const int* __restrict__ off, int* __restrict__ fill,
    int* __restrict__ tok, float* __restrict__ sc)
{
    int t = blockIdx.x * 256 + threadIdx.x;
    if (t >= TN) return;
#pragma unroll
    for (int k = 0; k < 2; ++k) {
        int e = tke[2 * t + k];
        int pos = off[e] + atomicAdd(&fill[e], 1);
        tok[pos] = t; sc[pos] = tks[2 * t + k];
    }
}

// ---------------- y init with score-weighted b_down ----------------
__global__ __launch_bounds__(256) void k_yinit(
    const int* __restrict__ tke, const float* __restrict__ tks,
    const float* __restrict__ bd, float* __restrict__ y)
{
    int t = blockIdx.x, tid = threadIdx.x;
    int e1 = tke[2 * t], e2 = tke[2 * t + 1];
    float s1 = tks[2 * t], s2 = tks[2 * t + 1];
    const float4* b1 = (const float4*)(bd + (size_t)e1 * DO);
    const float4* b2 = (const float4*)(bd + (size_t)e2 * DO);
    float4* yr = (float4*)(y + (size_t)t * DO);
#pragma unroll
    for (int j = 0; j < 4; ++j) {
        int i = j * 256 + tid;
        float4 a = b1[i], b = b2[i], r;
        r.x = s1 * a.x + s2 * b.x; r.y = s1 * a.y + s2 * b.y;
        r.z = s1 * a.z + s2 * b.z; r.w = s1 * a.w + s2 * b.w;
        yr[i] = r;
    }
}

// ============ m201-faithful 8-phase 256x256 GEMM kernels ============
// K-split half-tiles: each region = 256 rows x 32 K-cols bf16 (16 KB, 64B
// rows, 4 slots; XOR swizzle phys = slot ^ ((row>>1)&3), 2-way free).
// 8 regions (2 dbuf x {A,B} x {kh0,kh1}) = 128 KB. 512 thr, 8 waves 2Mx4N,
// wave tile 128x64, acc[8][4]. Per K-tile 4 phases:
//   ph1 (mh0,kk0): rd 4A+4B | stage A-kh1(t+1)->other dbuf | bar lgkm MFMA bar
//   ph2 (mh1,kk0): rd 4A    | stage B-kh0(t+2)             | ...
//   ph3 (mh0,kk1): rd 4A+4B | stage A-kh0(t+2)             | ...
//   ph4 (mh1,kk1): rd 4A    | stage B-kh1(t+2) | MFMA vmcnt(6) bar
// Rotation proof: each staged region's previous data was last ds_read one
// phase earlier (bar2-protected); vmcnt(6) leaves exactly the 3 t+2 halves
// in flight and guarantees all of t+1 landed. Tail: vmcnt(0) at tile NT-2.
// launch_bounds(512,2): 256-reg cap, no acc spill (r5 lesson); LDS dests
// wave-uniform (r3/4 lesson).

// ---------------- stage-1: fused GLU, B = [G;U] stacked ----------------
__global__ __launch_bounds__(512, 2) void k_s1m(
    const u16* __restrict__ x16,
    const u16* __restrict__ wg16, const u16* __restrict__ wu16,
    const float* __restrict__ bg, const float* __restrict__ bu,
    const int* __restrict__ cnt, const int* __restrict__ off,
    const int* __restrict__ tok, const float* __restrict__ sc,
    u16* __restrict__ inter)
{
    int e = blockIdx.x & 7;
    int ce = cnt[e];
    int rows0 = (blockIdx.x >> 3) * 256;
    if (rows0 >= ce) return;
    int oe = off[e];
    int h0 = blockIdx.y * 128;
    int tid = threadIdx.x;

    __shared__ u16 A0a[8192]; __shared__ u16 A1a[8192];
    __shared__ u16 B0a[8192]; __shared__ u16 B1a[8192];
    __shared__ u16 A0b[8192]; __shared__ u16 A1b[8192];
    __shared__ u16 B0b[8192]; __shared__ u16 B1b[8192];

    // staging: thread covers rows (tid>>2) and 128+(tid>>2), phys slot tid&3;
    // global logical slot = (tid&3) ^ ((tid>>3)&3)
    int swz = ((tid & 3) ^ ((tid >> 3) & 3)) * 8;
    const u16* apt0; const u16* apt1; const u16* bpt0; const u16* bpt1;
    {
        int r0 = tid >> 2;
        int ag0 = oe + min(rows0 + r0, ce - 1);
        int ag1 = oe + min(rows0 + 128 + r0, ce - 1);
        apt0 = x16 + (size_t)tok[ag0] * DI + swz;
        apt1 = x16 + (size_t)tok[ag1] * DI + swz;
        int hr = min(h0 + r0, DH - 1);
        bpt0 = wg16 + ((size_t)e * DH + hr) * DI + swz;   // B rows 0-127 = G
        bpt1 = wu16 + ((size_t)e * DH + hr) * DI + swz;   // B rows 128-255 = U
    }

    int wid = tid >> 6, lane = tid & 63;
    int wm = wid >> 2, wn = wid & 3;
    int l15 = lane & 15, qq = lane >> 4;
    int phq = ((qq ^ ((lane >> 1) & 3)) & 3) * 8;
    int rAoff = (wm * 128 + l15) * 32 + phq;
    int rBoff = (wn * 64 + l15) * 32 + phq;

    f32x4 acc[8][4];
    f32x4 vz = {0.f, 0.f, 0.f, 0.f};
#pragma unroll
    for (int m = 0; m < 8; ++m)
#pragma unroll
        for (int n = 0; n < 4; ++n) acc[m][n] = vz;

#define S1RD_A(L_, MH) { _Pragma("unroll") \
    for (int m = 0; m < 4; ++m) av[m] = *(const bf16x8*)&L_[rAoff + (MH)*2048 + m*512]; }
#define S1RD_B(L_) { _Pragma("unroll") \
    for (int n = 0; n < 4; ++n) bv[n] = *(const bf16x8*)&L_[rBoff + n*512]; }
#define S1MM(MB) { __builtin_amdgcn_s_setprio(1); \
    _Pragma("unroll") for (int m = 0; m < 4; ++m) \
    _Pragma("unroll") for (int n = 0; n < 4; ++n) \
        acc[(MB)+m][n] = __builtin_amdgcn_mfma_f32_16x16x32_bf16(av[m], bv[n], acc[(MB)+m][n], 0, 0, 0); \
    __builtin_amdgcn_s_setprio(0); }
#define S1STA(L_, K0) { gload16(apt0 + (K0), &L_[wid*512]); gload16(apt1 + (K0), &L_[4096 + wid*512]); }
#define S1STB(L_, K0) { gload16(bpt0 + (K0), &L_[wid*512]); gload16(bpt1 + (K0), &L_[4096 + wid*512]); }

#define S1_TILE(CA0_, CA1_, CB0_, CB1_, NA1_, KN1, KN2) \
  { bf16x8 av[4], bv[4]; \
    S1RD_A(CA0_, 0); S1RD_B(CB0_); S1STA(NA1_, (KN1) + 32); \
    BAR(); LGKM(); S1MM(0); BAR(); \
    S1RD_A(CA0_, 1); S1STB(CB0_, (KN2)); \
    BAR(); LGKM(); S1MM(4); BAR(); \
    S1RD_A(CA1_, 0); S1RD_B(CB1_); S1STA(CA0_, (KN2)); \
    BAR(); LGKM(); S1MM(0); BAR(); \
    S1RD_A(CA1_, 1); S1STB(CB1_, (KN2) + 32); \
    BAR(); LGKM(); S1MM(4); VMW(6); BAR(); }

    const int NT = DI / 64;   // 64, even
    // prologue: tile0 (4 halves) + tile1 (3 halves); vmcnt(6) -> tile0 landed
    S1STB(B0a, 0); S1STA(A0a, 0); S1STB(B1a, 32); S1STA(A1a, 32);
    S1STB(B0b, 64); S1STA(A0b, 64); S1STB(B1b, 96);
    VMW(6); BAR();

    for (int kt = 0; kt + 2 < NT; kt += 2) {
        S1_TILE(A0a, A1a, B0a, B1a, A1b, (kt + 1) * 64, (kt + 2) * 64);
        S1_TILE(A0b, A1b, B0b, B1b, A1a, (kt + 2) * 64, (kt + 3) * 64);
    }
    // tile NT-2 (d0): only ph1 stage (A-kh1 of NT-1); drain at ph4
    { bf16x8 av[4], bv[4];
      S1RD_A(A0a, 0); S1RD_B(B0a); S1STA(A1b, (NT - 1) * 64 + 32);
      BAR(); LGKM(); S1MM(0); BAR();
      S1RD_A(A0a, 1);
      BAR(); LGKM(); S1MM(4); BAR();
      S1RD_A(A1a, 0); S1RD_B(B1a);
      BAR(); LGKM(); S1MM(0); BAR();
      S1RD_A(A1a, 1);
      BAR(); LGKM(); S1MM(4); VMW(0); BAR();
      // tile NT-1 (d1): no stages
      S1RD_A(A0b, 0); S1RD_B(B0b); BAR(); LGKM(); S1MM(0); BAR();
      S1RD_A(A0b, 1); BAR(); LGKM(); S1MM(4); BAR();
      S1RD_A(A1b, 0); S1RD_B(B1b); BAR(); LGKM(); S1MM(0); BAR();
      S1RD_A(A1b, 1); BAR(); LGKM(); S1MM(4); BAR();
    }
#undef S1_TILE
#undef S1STA
#undef S1STB
#undef S1RD_A
#undef S1RD_B
#undef S1MM

    // ---- epilogue: U-waves (wn>=2) export acc via LDS; G-waves combine ----
    int r4 = wm * 2 + ((wn >= 2) ? (wn - 2) : wn);
    u16* e0 = (r4 == 0) ? B0a : (r4 == 1) ? B1a : (r4 == 2) ? B0b : B1b;
    u16* e1 = (r4 == 0) ? A0a : (r4 == 1) ? A1a : (r4 == 2) ? A0b : A1b;

    if (wn >= 2) {
#pragma unroll
        for (int m = 0; m < 8; ++m)
#pragma unroll
            for (int n = 0; n < 4; ++n) {
                int s = m * 4 + n;
                u16* p = (s < 16) ? (e0 + s * 512) : (e1 + (s - 16) * 512);
                *(f32x4*)&p[lane * 8] = acc[m][n];
            }
    }
    __syncthreads();
    if (wn < 2) {
        int rmax = ce - rows0;
        float bgv[4], buv[4];
        int hc[4]; bool hok[4];
#pragma unroll
        for (int n = 0; n < 4; ++n) {
            hc[n] = h0 + wn * 64 + n * 16 + l15;
            hok[n] = hc[n] < DH;
            bgv[n] = hok[n] ? bg[e * DH + hc[n]] : 0.f;
            buv[n] = hok[n] ? bu[e * DH + hc[n]] : 0.f;
        }
#pragma unroll
        for (int m = 0; m < 8; ++m) {
            f32x4 uv4[4];
#pragma unroll
            for (int n = 0; n < 4; ++n) {
                int s = m * 4 + n;
                const u16* p = (s < 16) ? (e0 + s * 512) : (e1 + (s - 16) * 512);
                uv4[n] = *(const f32x4*)&p[lane * 8];
            }
#pragma unroll
            for (int r = 0; r < 4; ++r) {
                int rl = wm * 128 + m * 16 + qq * 4 + r;
                if (rl < rmax) {
                    int rg = oe + rows0 + rl;
                    float s = sc[rg];
                    size_t rowb = (size_t)rg * DHP;
#pragma unroll
                    for (int n = 0; n < 4; ++n) {
                        float v = 0.f;
                        if (hok[n]) {
                            float gv = acc[m][n][r] + bgv[n];
                            float uu = uv4[n][r] + buv[n];
                            float sig = 1.0f / (1.0f + __expf(-gv));
                            v = s * gv * sig * uu;
                        }
                        inter[rowb + hc[n]] = f2bf(v);
                    }
                }
            }
        }
    }
}

// ---------------- stage-2: down-proj 256x256 + atomic scatter ----------------
__global__ __launch_bounds__(512, 2) void k_s2m(
    const u16* __restrict__ inter, const u16* __restrict__ wd16,
    const int* __restrict__ cnt, const int* __restrict__ off,
    const int* __restrict__ tok, float* __restrict__ y)
{
    int e = blockIdx.x & 7;
    int ce = cnt[e];
    int rows0 = (blockIdx.x >> 3) * 256;
    if (rows0 >= ce) return;
    int oe = off[e];
    int o0 = blockIdx.y * 256;
    int tid = threadIdx.x;

    __shared__ u16 A0a[8192]; __shared__ u16 A1a[8192];
    __shared__ u16 B0a[8192]; __shared__ u16 B1a[8192];
    __shared__ u16 A0b[8192]; __shared__ u16 A1b[8192];
    __shared__ u16 B0b[8192]; __shared__ u16 B1b[8192];

    int swz = ((tid & 3) ^ ((tid >> 3) & 3)) * 8;
    const u16* apt0; const u16* apt1; const u16* bpt0; const u16* bpt1;
    {
        int r0 = tid >> 2;
        int ag0 = min(oe + rows0 + r0, NPAIR - 1);
        int ag1 = min(oe + rows0 + 128 + r0, NPAIR - 1);
        apt0 = inter + (size_t)ag0 * DHP + swz;
        apt1 = inter + (size_t)ag1 * DHP + swz;
        bpt0 = wd16 + ((size_t)e * DO + (o0 + r0)) * DHP + swz;
        bpt1 = wd16 + ((size_t)e * DO + (o0 + 128 + r0)) * DHP + swz;
    }

    int wid = tid >> 6, lane = tid & 63;
    int wm = wid >> 2, wn = wid & 3;
    int l15 = lane & 15, qq = lane >> 4;
    int phq = ((qq ^ ((lane >> 1) & 3)) & 3) * 8;
    int rAoff = (wm * 128 + l15) * 32 + phq;
    int rBoff = (wn * 64 + l15) * 32 + phq;

    f32x4 acc[8][4];
    f32x4 vz = {0.f, 0.f, 0.f, 0.f};
#pragma unroll
    for (int m = 0; m < 8; ++m)
#pragma unroll
        for (int n = 0; n < 4; ++n) acc[m][n] = vz;

#define S2RD_A(L_, MH) { _Pragma("unroll") \
    for (int m = 0; m < 4; ++m) av[m] = *(const bf16x8*)&L_[rAoff + (MH)*2048 + m*512]; }
#define S2RD_B(L_) { _Pragma("unroll") \
    for (int n = 0; n < 4; ++n) bv[n] = *(const bf16x8*)&L_[rBoff + n*512]; }
#define S2MM(MB) { __builtin_amdgcn_s_setprio(1); \
    _Pragma("unroll") for (int m = 0; m < 4; ++m) \
    _Pragma("unroll") for (int n = 0; n < 4; ++n) \
        acc[(MB)+m][n] = __builtin_amdgcn_mfma_f32_16x16x32_bf16(av[m], bv[n], acc[(MB)+m][n], 0, 0, 0); \
    __builtin_amdgcn_s_setprio(0); }
#define S2STA(L_, K0) { gload16(apt0 + (K0), &L_[wid*512]); gload16(apt1 + (K0), &L_[4096 + wid*512]); }
#define S2STB(L_, K0) { gload16(bpt0 + (K0), &L_[wid*512]); gload16(bpt1 + (K0), &L_[4096 + wid*512]); }

#define S2_TILE(CA0_, CA1_, CB0_, CB1_, NA1_, KN1, KN2) \
  { bf16x8 av[4], bv[4]; \
    S2RD_A(CA0_, 0); S2RD_B(CB0_); S2STA(NA1_, (KN1) + 32); \
    BAR(); LGKM(); S2MM(0); BAR(); \
    S2RD_A(CA0_, 1); S2STB(CB0_, (KN2)); \
    BAR(); LGKM(); S2MM(4); BAR(); \
    S2RD_A(CA1_, 0); S2RD_B(CB1_); S2STA(CA0_, (KN2)); \
    BAR(); LGKM(); S2MM(0); BAR(); \
    S2RD_A(CA1_, 1); S2STB(CB1_, (KN2) + 32); \
    BAR(); LGKM(); S2MM(4); VMW(6); BAR(); }

    const int NT = DHP / 64;   // 22, even
    S2STB(B0a, 0); S2STA(A0a, 0); S2STB(B1a, 32); S2STA(A1a, 32);
    S2STB(B0b, 64); S2STA(A0b, 64); S2STB(B1b, 96);
    VMW(6); BAR();

    for (int kt = 0; kt + 2 < NT; kt += 2) {
        S2_TILE(A0a, A1a, B0a, B1a, A1b, (kt + 1) * 64, (kt + 2) * 64);
        S2_TILE(A0b, A1b, B0b, B1b, A1a, (kt + 2) * 64, (kt + 3) * 64);
    }
    { bf16x8 av[4], bv[4];
      S2RD_A(A0a, 0); S2RD_B(B0a); S2STA(A1b, (NT - 1) * 64 + 32);
      BAR(); LGKM(); S2MM(0); BAR();
      S2RD_A(A0a, 1);
      BAR(); LGKM(); S2MM(4); BAR();
      S2RD_A(A1a, 0); S2RD_B(B1a);
      BAR(); LGKM(); S2MM(0); BAR();
      S2RD_A(A1a, 1);
      BAR(); LGKM(); S2MM(4); VMW(0); BAR();
      S2RD_A(A0b, 0); S2RD_B(B0b); BAR(); LGKM(); S2MM(0); BAR();
      S2RD_A(A0b, 1); BAR(); LGKM(); S2MM(4); BAR();
      S2RD_A(A1b, 0); S2RD_B(B1b); BAR(); LGKM(); S2MM(0); BAR();
      S2RD_A(A1b, 1); BAR(); LGKM(); S2MM(4); BAR();
    }
#undef S2_TILE
#undef S2STA
#undef S2STB
#undef S2RD_A
#undef S2RD_B
#undef S2MM

    int rmax = ce - rows0;
#pragma unroll
    for (int m = 0; m < 8; ++m) {
#pragma unroll
        for (int r = 0; r < 4; ++r) {
            int rl = wm * 128 + m * 16 + qq * 4 + r;
            if (rl >= rmax) continue;
            int t = tok[oe + rows0 + rl];
            float* yr = y + (size_t)t * DO + o0 + wn * 64 + l15;
#pragma unroll
            for (int n = 0; n < 4; ++n)
                unsafeAtomicAdd(yr + n * 16, acc[m][n][r]);
        }
    }
}

// ---------------- host launch ----------------
extern "C" void kernel_launch(void* const* d_in, const int* in_sizes, int n_in,
                              void* d_out, int out_size, void* d_ws, size_t ws_size,
                              hipStream_t stream)
{
    const float* x  = (const float*)d_in[0];
    const float* gw = (const float*)d_in[1];
    const float* wg = (const float*)d_in[2];
    const float* bg = (const float*)d_in[3];
    const float* wu = (const float*)d_in[4];
    const float* bu = (const float*)d_in[5];
    const float* wd = (const float*)d_in[6];
    const float* bd = (const float*)d_in[7];
    float* y = (float*)d_out;
    float* loss = y + (size_t)TN * DO;

    uint8_t* ws = (uint8_t*)d_ws;
    u16*   x16   = (u16*)(ws + 0);             // 33,554,432
    u16*   inter = (u16*)(ws + 33554432ull);   // 23,068,672 (stride DHP)
    u16*   wg16  = (u16*)(ws + 56623104ull);   // 90,177,536
    u16*   wu16  = (u16*)(ws + 146800640ull);  // 90,177,536
    u16*   wd16  = (u16*)(ws + 236978176ull);  // 92,274,688 (stride DHP, pad zeroed)
    int*   tok   = (int*)(ws + 329252864ull);
    float* sc    = (float*)(ws + 329285632ull);
    int*   tke   = (int*)(ws + 329318400ull);
    float* tks   = (float*)(ws + 329351168ull);
    int*   misc  = (int*)(ws + 329383936ull);
    int* cnt = misc; int* fill = misc + 8; int* off = misc + 16;
    float* imp = (float*)(misc + 24);

    hipMemsetAsync(misc, 0, 128, stream);
    k_cvt_all<<<66560, 256, 0, stream>>>(wg, wu, wd, wg16, wu16, wd16);
    k_gate<<<TN, 256, 0, stream>>>(x, gw, x16, tke, tks, cnt, imp);
    k_finalize<<<1, 64, 0, stream>>>(cnt, imp, off, loss);
    k_scatter<<<TN / 256, 256, 0, stream>>>(tke, tks, off, fill, tok, sc);
    k_yinit<<<TN, 256, 0, stream>>>(tke, tks, bd, y);
    k_s1m<<<dim3(128, 11), 512, 0, stream>>>(x16, wg16, wu16, bg, bu, cnt, off, tok, sc, inter);
    k_s2m<<<dim3(128, 16), 512, 0, stream>>>(inter, wd16, cnt, off, tok, y);
}

// Round 12
// 787.153 us; speedup vs baseline: 1.2226x; 1.1143x over previous
//
#include <hip/hip_runtime.h>
#include <hip/hip_bf16.h>
#include <stdint.h>

#define TN 4096      // tokens (B*S)
#define DI 4096      // input dim
#define DH 1376      // GLU hidden dim
#define DHP 1408     // padded hidden (22*64, 44*32)
#define DO 4096      // output dim
#define NE 8         // experts
#define NPAIR 8192   // TN * K

typedef unsigned short u16;
typedef __bf16 bf16x8 __attribute__((ext_vector_type(8)));
typedef float f32x4 __attribute__((ext_vector_type(4)));
typedef uint32_t u32x4 __attribute__((ext_vector_type(4)));

__device__ __forceinline__ uint32_t pack2bf(float a, float b) {
    union { float f; uint32_t u; } ua, ub;
    ua.f = a; ub.f = b;
    uint32_t lo = (ua.u + 0x7fffu + ((ua.u >> 16) & 1u)) >> 16;
    uint32_t hi = (ub.u + 0x7fffu + ((ub.u >> 16) & 1u)) >> 16;
    return lo | (hi << 16);
}
__device__ __forceinline__ u16 f2bf(float a) {
    union { float f; uint32_t u; } ua; ua.f = a;
    return (u16)((ua.u + 0x7fffu + ((ua.u >> 16) & 1u)) >> 16);
}
__device__ __forceinline__ void gload16(const void* g, void* l) {
    __builtin_amdgcn_global_load_lds(
        (const __attribute__((address_space(1))) void*)g,
        (__attribute__((address_space(3))) void*)l, 16, 0, 0);
}
#define MEMFENCE() asm volatile("" ::: "memory")

// ---------------- fused: weight convert (bulk BW) + gate (compute) ----------------
// Gate blocks first (0..4095) so their latency hides under the 912MB cvt stream.
// cvt regions: wg (5,636,096 x8), wu (same), wd [8*4096][1376]->[..][1408] with
// pad col 1376 = b_down[row] (bias folded into stage-2 GEMM K-dim).
__global__ __launch_bounds__(256) void k_cvt_gate(
    const float* __restrict__ x, const float* __restrict__ gw,
    const float* __restrict__ wg, const float* __restrict__ wu,
    const float* __restrict__ wd, const float* __restrict__ bd,
    u16* __restrict__ x16, u16* __restrict__ wg16, u16* __restrict__ wu16,
    u16* __restrict__ wd16,
    int* __restrict__ tke, float* __restrict__ tks,
    int* __restrict__ cnt, float* __restrict__ imp)
{
    int tid = threadIdx.x;
    if (blockIdx.x < TN) {
        // ---- gate branch: one token per block, f64-accurate logits ----
        int t = blockIdx.x;
        const float* xr = x + (size_t)t * DI;
        double acc[NE];
#pragma unroll
        for (int e = 0; e < NE; ++e) acc[e] = 0.0;
#pragma unroll
        for (int j = 0; j < 4; ++j) {
            int i4 = (j * 256 + tid) * 4;
            float4 xv = *(const float4*)(xr + i4);
            uint2 p; p.x = pack2bf(xv.x, xv.y); p.y = pack2bf(xv.z, xv.w);
            *(uint2*)(x16 + (size_t)t * DI + i4) = p;
#pragma unroll
            for (int e = 0; e < NE; ++e) {
                float4 wv = *(const float4*)(gw + (size_t)e * DI + i4);
                acc[e] = fma((double)xv.x, (double)wv.x, acc[e]);
                acc[e] = fma((double)xv.y, (double)wv.y, acc[e]);
                acc[e] = fma((double)xv.z, (double)wv.z, acc[e]);
                acc[e] = fma((double)xv.w, (double)wv.w, acc[e]);
            }
        }
#pragma unroll
        for (int o = 32; o > 0; o >>= 1)
#pragma unroll
            for (int e = 0; e < NE; ++e) acc[e] += __shfl_down(acc[e], o, 64);
        __shared__ double lred[4][NE];
        if ((tid & 63) == 0)
#pragma unroll
            for (int e = 0; e < NE; ++e) lred[tid >> 6][e] = acc[e];
        __syncthreads();
        if (tid == 0) {
            double lg[NE];
#pragma unroll
            for (int e = 0; e < NE; ++e) lg[e] = lred[0][e] + lred[1][e] + lred[2][e] + lred[3][e];
            int e1 = 0;
            for (int e = 1; e < NE; ++e) if (lg[e] > lg[e1]) e1 = e;
            int e2 = -1;
            for (int e = 0; e < NE; ++e) { if (e == e1) continue; if (e2 < 0 || lg[e] > lg[e2]) e2 = e; }
            float d = (float)(lg[e2] - lg[e1]);
            float ed = expf(d);
            float s1 = 1.0f / (1.0f + ed);
            float s2 = ed / (1.0f + ed);
            tke[2 * t] = e1; tke[2 * t + 1] = e2;
            tks[2 * t] = s1; tks[2 * t + 1] = s2;
            atomicAdd(&cnt[e1], 1); atomicAdd(&cnt[e2], 1);
            unsafeAtomicAdd(&imp[e1], s1); unsafeAtomicAdd(&imp[e2], s2);
        }
        return;
    }
    // ---- cvt branch ----
    int i = (blockIdx.x - TN) * 256 + tid;
    if (i < 11272192) {
        const float* src = (i < 5636096) ? wg : wu;
        u16* dst = (i < 5636096) ? wg16 : wu16;
        int j = (i < 5636096) ? i : i - 5636096;
        const float4* s = (const float4*)(src + (size_t)j * 8);
        float4 a = s[0], b = s[1];
        u32x4 v = {pack2bf(a.x, a.y), pack2bf(a.z, a.w), pack2bf(b.x, b.y), pack2bf(b.z, b.w)};
        *(u32x4*)(dst + (size_t)j * 8) = v;
    } else {
        int j = i - 11272192;
        if (j >= 5767168) return;
        int row = j / 176, c8 = (j % 176) * 8;
        u32x4 v = {0u, 0u, 0u, 0u};
        if (c8 < DH) {
            const float4* s = (const float4*)(wd + (size_t)row * DH + c8);
            float4 a = s[0], b = s[1];
            v = (u32x4){pack2bf(a.x, a.y), pack2bf(a.z, a.w), pack2bf(b.x, b.y), pack2bf(b.z, b.w)};
        } else if (c8 == DH) {
            // pad col 1376 carries b_down: GEMM K-dim picks up score*b_down
            v.x = (uint32_t)f2bf(bd[row]);
        }
        *(u32x4*)(wd16 + (size_t)row * DHP + c8) = v;
    }
}

// ---------------- scatter + finalize (off/loss) ----------------
__global__ __launch_bounds__(256) void k_scatter_fin(
    const int* __restrict__ tke, const float* __restrict__ tks,
    const int* __restrict__ cnt, const float* __restrict__ imp,
    int* __restrict__ off, int* __restrict__ fill,
    int* __restrict__ tok, float* __restrict__ sc, float* __restrict__ loss_out)
{
    int loc[NE]; int o = 0;
#pragma unroll
    for (int e = 0; e < NE; ++e) { loc[e] = o; o += cnt[e]; }
    if (blockIdx.x == 0 && threadIdx.x == 0) {
#pragma unroll
        for (int e = 0; e < NE; ++e) off[e] = loc[e];
        float m1 = 0.f, m2 = 0.f;
        for (int e = 0; e < NE; ++e) { m1 += imp[e]; m2 += (float)cnt[e]; }
        m1 *= 0.125f; m2 *= 0.125f;
        float v1 = 0.f, v2 = 0.f;
        for (int e = 0; e < NE; ++e) {
            float d1 = imp[e] - m1, d2 = (float)cnt[e] - m2;
            v1 += d1 * d1; v2 += d2 * d2;
        }
        v1 /= 7.0f; v2 /= 7.0f;
        *loss_out = 0.01f * (v1 / (m1 * m1 + 1e-10f) + v2 / (m2 * m2 + 1e-10f));
    }
    int t = blockIdx.x * 256 + threadIdx.x;
    if (t >= TN) return;
#pragma unroll
    for (int k = 0; k < 2; ++k) {
        int e = tke[2 * t + k];
        int pos = loc[e] + atomicAdd(&fill[e], 1);
        tok[pos] = t; sc[pos] = tks[2 * t + k];
    }
}

// ============ stage-1: round-7 best (3-buffer counted vmcnt) ============
// + epilogue writes score into inter pad col 1376 (stage-2 bias fold).
__global__ __launch_bounds__(256, 2) void k_stage1g(
    const u16* __restrict__ x16,
    const u16* __restrict__ wg16, const u16* __restrict__ wu16,
    const float* __restrict__ bg, const float* __restrict__ bu,
    const int* __restrict__ cnt, const int* __restrict__ off,
    const int* __restrict__ tok, const float* __restrict__ sc,
    u16* __restrict__ inter)
{
    int e = blockIdx.x & 7;
    int ce = cnt[e];
    int rows0 = (blockIdx.x >> 3) * 128;
    if (rows0 >= ce) return;
    int oe = off[e];
    int h0 = blockIdx.y * 128;
    int tid = threadIdx.x;

    __shared__ u16 As0[128 * 32]; __shared__ u16 As1[128 * 32]; __shared__ u16 As2[128 * 32];
    __shared__ u16 Gs0[128 * 32]; __shared__ u16 Gs1[128 * 32]; __shared__ u16 Gs2[128 * 32];
    __shared__ u16 Us0[128 * 32]; __shared__ u16 Us1[128 * 32]; __shared__ u16 Us2[128 * 32];

    int swz = ((tid & 3) ^ ((tid >> 3) & 3)) * 8;
    const u16* ab0; const u16* ab1; const u16* gb0; const u16* gb1;
    const u16* ub0; const u16* ub1;
    {
        int rl0 = tid >> 2, rl1 = 64 + (tid >> 2);
        int rg0 = oe + min(rows0 + rl0, ce - 1);
        int rg1 = oe + min(rows0 + rl1, ce - 1);
        ab0 = x16 + (size_t)tok[rg0] * DI + swz;
        ab1 = x16 + (size_t)tok[rg1] * DI + swz;
        int hr0 = min(h0 + rl0, DH - 1), hr1 = min(h0 + rl1, DH - 1);
        gb0 = wg16 + ((size_t)e * DH + hr0) * DI + swz;
        gb1 = wg16 + ((size_t)e * DH + hr1) * DI + swz;
        ub0 = wu16 + ((size_t)e * DH + hr0) * DI + swz;
        ub1 = wu16 + ((size_t)e * DH + hr1) * DI + swz;
    }

    int wid = tid >> 6, lane = tid & 63;
    int ldsw = wid * 512;
    int wm = wid >> 1, wn = wid & 1;
    int rA = wm * 64 + (lane & 15);
    int rB = wn * 64 + (lane & 15);
    int colb = (((lane >> 4) ^ ((lane >> 1) & 3)) & 3) * 8;

    f32x4 accg[4][4], accu[4][4];
    f32x4 vz = {0.f, 0.f, 0.f, 0.f};
#pragma unroll
    for (int m = 0; m < 4; ++m)
#pragma unroll
        for (int n = 0; n < 4; ++n) { accg[m][n] = vz; accu[m][n] = vz; }

#define S1_STAGE(A_, G_, U_, K0)                                   \
    do {                                                           \
        gload16(ab0 + (K0), &A_[ldsw]);                            \
        gload16(ab1 + (K0), &A_[2048 + ldsw]);                     \
        gload16(gb0 + (K0), &G_[ldsw]);                            \
        gload16(gb1 + (K0), &G_[2048 + ldsw]);                     \
        gload16(ub0 + (K0), &U_[ldsw]);                            \
        gload16(ub1 + (K0), &U_[2048 + ldsw]);                     \
    } while (0)

#define S1_COMPUTE(A_, G_, U_)                                     \
    do {                                                           \
        bf16x8 a[4], g[4], u[4];                                   \
        _Pragma("unroll")                                          \
        for (int m = 0; m < 4; ++m)                                \
            a[m] = *(const bf16x8*)&A_[(rA + m * 16) * 32 + colb]; \
        _Pragma("unroll")                                          \
        for (int n = 0; n < 4; ++n) {                              \
            g[n] = *(const bf16x8*)&G_[(rB + n * 16) * 32 + colb]; \
            u[n] = *(const bf16x8*)&U_[(rB + n * 16) * 32 + colb]; \
        }                                                          \
        __builtin_amdgcn_s_setprio(1);                             \
        _Pragma("unroll")                                          \
        for (int m = 0; m < 4; ++m)                                \
            _Pragma("unroll")                                      \
            for (int n = 0; n < 4; ++n) {                          \
                accg[m][n] = __builtin_amdgcn_mfma_f32_16x16x32_bf16(a[m], g[n], accg[m][n], 0, 0, 0); \
                accu[m][n] = __builtin_amdgcn_mfma_f32_16x16x32_bf16(a[m], u[n], accu[m][n], 0, 0, 0); \
            }                                                      \
        __builtin_amdgcn_s_setprio(0);                             \
    } while (0)

#define S1_PHASE(A_, G_, U_, KN)                                   \
    do {                                                           \
        asm volatile("s_waitcnt vmcnt(12)" ::: "memory");          \
        __builtin_amdgcn_s_barrier();                              \
        MEMFENCE();                                                \
        S1_COMPUTE(A_, G_, U_);                                    \
        __builtin_amdgcn_s_barrier();                              \
        MEMFENCE();                                                \
        S1_STAGE(A_, G_, U_, KN);                                  \
    } while (0)

    const int NT = DI / 32;        // 128
    const int KL = (NT - 1) * 32;
    S1_STAGE(As0, Gs0, Us0, 0);
    S1_STAGE(As1, Gs1, Us1, 32);
    S1_STAGE(As2, Gs2, Us2, 64);

    for (int kt = 0; kt + 4 < NT; kt += 3) {
        S1_PHASE(As0, Gs0, Us0, min((kt + 3) * 32, KL));
        S1_PHASE(As1, Gs1, Us1, min((kt + 4) * 32, KL));
        S1_PHASE(As2, Gs2, Us2, min((kt + 5) * 32, KL));
    }
    asm volatile("s_waitcnt vmcnt(12)" ::: "memory");
    __builtin_amdgcn_s_barrier();
    MEMFENCE();
    S1_COMPUTE(As0, Gs0, Us0);
    asm volatile("s_waitcnt vmcnt(6)" ::: "memory");
    __builtin_amdgcn_s_barrier();
    MEMFENCE();
    S1_COMPUTE(As1, Gs1, Us1);
    asm volatile("s_waitcnt vmcnt(0)" ::: "memory");
#undef S1_STAGE
#undef S1_COMPUTE
#undef S1_PHASE

    int rmax = ce - rows0;
    float bgv[4], buv[4];
    int hc[4]; bool hok[4];
#pragma unroll
    for (int n = 0; n < 4; ++n) {
        hc[n] = h0 + wn * 64 + n * 16 + (lane & 15);
        hok[n] = hc[n] < DH;
        bgv[n] = hok[n] ? bg[e * DH + hc[n]] : 0.f;
        buv[n] = hok[n] ? bu[e * DH + hc[n]] : 0.f;
    }
#pragma unroll
    for (int m = 0; m < 4; ++m) {
#pragma unroll
        for (int r = 0; r < 4; ++r) {
            int rl = wm * 64 + m * 16 + (lane >> 4) * 4 + r;
            if (rl < rmax) {
                int rg = oe + rows0 + rl;
                float s = sc[rg];
                size_t rowb = (size_t)rg * DHP;
#pragma unroll
                for (int n = 0; n < 4; ++n) {
                    float v = 0.f;
                    if (hok[n]) {
                        float gv = accg[m][n][r] + bgv[n];
                        float uv = accu[m][n][r] + buv[n];
                        float sig = 1.0f / (1.0f + __expf(-gv));
                        v = s * gv * sig * uv;
                    } else if (hc[n] == DH) {
                        v = s;          // bias-fold: pairs with wd16 col 1376
                    }
                    inter[rowb + hc[n]] = f2bf(v);
                }
            }
        }
    }
}

// ============ stage-2: round-8 best (2-buffer counted vmcnt, 32KB LDS) ============
__global__ __launch_bounds__(256, 2) void k_stage2h(
    const u16* __restrict__ inter, const u16* __restrict__ wd16,
    const int* __restrict__ cnt, const int* __restrict__ off,
    const int* __restrict__ tok, float* __restrict__ y)
{
    int e = blockIdx.x & 7;
    int ce = cnt[e];
    int rows0 = (blockIdx.x >> 3) * 128;
    if (rows0 >= ce) return;
    int oe = off[e];
    int o0 = blockIdx.y * 128;
    int tid = threadIdx.x;

    __shared__ u16 As0[128 * 32]; __shared__ u16 As1[128 * 32];
    __shared__ u16 Bs0[128 * 32]; __shared__ u16 Bs1[128 * 32];

    int swz = ((tid & 3) ^ ((tid >> 3) & 3)) * 8;
    const u16* ab0; const u16* ab1; const u16* bb0; const u16* bb1;
    {
        int rl0 = tid >> 2, rl1 = 64 + (tid >> 2);
        int ar0 = min(oe + rows0 + rl0, NPAIR - 1);
        int ar1 = min(oe + rows0 + rl1, NPAIR - 1);
        ab0 = inter + (size_t)ar0 * DHP + swz;
        ab1 = inter + (size_t)ar1 * DHP + swz;
        bb0 = wd16 + ((size_t)e * DO + (o0 + rl0)) * DHP + swz;
        bb1 = wd16 + ((size_t)e * DO + (o0 + rl1)) * DHP + swz;
    }

    int wid = tid >> 6, lane = tid & 63;
    int ldsw = wid * 512;
    int wm = wid >> 1, wn = wid & 1;
    int rA = wm * 64 + (lane & 15);
    int rB = wn * 64 + (lane & 15);
    int colb = (((lane >> 4) ^ ((lane >> 1) & 3)) & 3) * 8;

    f32x4 acc[4][4];
    f32x4 vz = {0.f, 0.f, 0.f, 0.f};
#pragma unroll
    for (int m = 0; m < 4; ++m)
#pragma unroll
        for (int n = 0; n < 4; ++n) acc[m][n] = vz;

#define S2_STAGE(A_, B_, K0)                                       \
    do {                                                           \
        gload16(ab0 + (K0), &A_[ldsw]);                            \
        gload16(ab1 + (K0), &A_[2048 + ldsw]);                     \
        gload16(bb0 + (K0), &B_[ldsw]);                            \
        gload16(bb1 + (K0), &B_[2048 + ldsw]);                     \
    } while (0)

#define S2_COMPUTE(A_, B_)                                         \
    do {                                                           \
        bf16x8 a[4], b[4];                                         \
        _Pragma("unroll")                                          \
        for (int m = 0; m < 4; ++m)                                \
            a[m] = *(const bf16x8*)&A_[(rA + m * 16) * 32 + colb]; \
        _Pragma("unroll")                                          \
        for (int n = 0; n < 4; ++n)                                \
            b[n] = *(const bf16x8*)&B_[(rB + n * 16) * 32 + colb]; \
        __builtin_amdgcn_s_setprio(1);                             \
        _Pragma("unroll")                                          \
        for (int m = 0; m < 4; ++m)                                \
            _Pragma("unroll")                                      \
            for (int n = 0; n < 4; ++n)                            \
                acc[m][n] = __builtin_amdgcn_mfma_f32_16x16x32_bf16(a[m], b[n], acc[m][n], 0, 0, 0); \
        __builtin_amdgcn_s_setprio(0);                             \
    } while (0)

    const int NT = DHP / 32;       // 44, even
    S2_STAGE(As0, Bs0, 0);
    S2_STAGE(As1, Bs1, 32);

    for (int kt = 0; kt < NT - 2; kt += 2) {
        asm volatile("s_waitcnt vmcnt(4)" ::: "memory");
        __builtin_amdgcn_s_barrier();
        MEMFENCE();
        S2_COMPUTE(As0, Bs0);
        __builtin_amdgcn_s_barrier();
        MEMFENCE();
        S2_STAGE(As0, Bs0, (kt + 2) * 32);
        asm volatile("s_waitcnt vmcnt(4)" ::: "memory");
        __builtin_amdgcn_s_barrier();
        MEMFENCE();
        S2_COMPUTE(As1, Bs1);
        __builtin_amdgcn_s_barrier();
        MEMFENCE();
        S2_STAGE(As1, Bs1, (kt + 3) * 32);
    }
    asm volatile("s_waitcnt vmcnt(4)" ::: "memory");
    __builtin_amdgcn_s_barrier();
    MEMFENCE();
    S2_COMPUTE(As0, Bs0);
    asm volatile("s_waitcnt vmcnt(0)" ::: "memory");
    __builtin_amdgcn_s_barrier();
    MEMFENCE();
    S2_COMPUTE(As1, Bs1);
#undef S2_STAGE
#undef S2_COMPUTE

    int rmax = ce - rows0;
#pragma unroll
    for (int m = 0; m < 4; ++m) {
#pragma unroll
        for (int r = 0; r < 4; ++r) {
            int rl = wm * 64 + m * 16 + (lane >> 4) * 4 + r;
            if (rl >= rmax) continue;
            int t = tok[oe + rows0 + rl];
            float* yr = y + (size_t)t * DO + o0 + wn * 64 + (lane & 15);
#pragma unroll
            for (int n = 0; n < 4; ++n)
                unsafeAtomicAdd(yr + n * 16, acc[m][n][r]);
        }
    }
}

// ---------------- host launch ----------------
extern "C" void kernel_launch(void* const* d_in, const int* in_sizes, int n_in,
                              void* d_out, int out_size, void* d_ws, size_t ws_size,
                              hipStream_t stream)
{
    const float* x  = (const float*)d_in[0];
    const float* gw = (const float*)d_in[1];
    const float* wg = (const float*)d_in[2];
    const float* bg = (const float*)d_in[3];
    const float* wu = (const float*)d_in[4];
    const float* bu = (const float*)d_in[5];
    const float* wd = (const float*)d_in[6];
    const float* bd = (const float*)d_in[7];
    float* y = (float*)d_out;
    float* loss = y + (size_t)TN * DO;

    uint8_t* ws = (uint8_t*)d_ws;
    u16*   x16   = (u16*)(ws + 0);             // 33,554,432
    u16*   inter = (u16*)(ws + 33554432ull);   // 23,068,672 (stride DHP)
    u16*   wg16  = (u16*)(ws + 56623104ull);   // 90,177,536
    u16*   wu16  = (u16*)(ws + 146800640ull);  // 90,177,536
    u16*   wd16  = (u16*)(ws + 236978176ull);  // 92,274,688 (stride DHP; col1376=b_down)
    int*   tok   = (int*)(ws + 329252864ull);
    float* sc    = (float*)(ws + 329285632ull);
    int*   tke   = (int*)(ws + 329318400ull);
    float* tks   = (float*)(ws + 329351168ull);
    int*   misc  = (int*)(ws + 329383936ull);
    int* cnt = misc; int* fill = misc + 8; int* off = misc + 16;
    float* imp = (float*)(misc + 24);

    hipMemsetAsync(misc, 0, 128, stream);
    hipMemsetAsync(d_out, 0, (size_t)out_size * 4, stream);   // y=0 (+loss slot)
    // fused cvt + gate: 4096 gate blocks + 66560 cvt blocks
    k_cvt_gate<<<70656, 256, 0, stream>>>(x, gw, wg, wu, wd, bd,
                                          x16, wg16, wu16, wd16,
                                          tke, tks, cnt, imp);
    k_scatter_fin<<<16, 256, 0, stream>>>(tke, tks, cnt, imp, off, fill, tok, sc, loss);
    k_stage1g<<<dim3(256, 11), 256, 0, stream>>>(x16, wg16, wu16, bg, bu, cnt, off, tok, sc, inter);
    k_stage2h<<<dim3(256, 32), 256, 0, stream>>>(inter, wd16, cnt, off, tok, y);
}